// Round 11
// baseline (2107.654 us; speedup 1.0000x reference)
//
#include <hip/hip_runtime.h>
#include <stdint.h>

#define DD 256
#define DINF 128

typedef __attribute__((ext_vector_type(8))) short short8;
typedef __attribute__((ext_vector_type(4))) float f32x4;

__device__ __forceinline__ short f2bf(float f) {
    union { float f; uint32_t u; } c{f};
    uint32_t r = (c.u + 0x7fffu + ((c.u >> 16) & 1u)) >> 16;
    return (short)(uint16_t)r;
}

__device__ __forceinline__ float bf2f(uint16_t b) {
    union { uint32_t u; float f; } c;
    c.u = ((uint32_t)b) << 16;
    return c.f;
}

// ---------------- CSR build ----------------
__global__ void k_hist(const int* __restrict__ rows, int* __restrict__ counts, int E) {
    int e = blockIdx.x * blockDim.x + threadIdx.x;
    if (e < E) atomicAdd(&counts[rows[e] + 1], 1);
}

__global__ void k_scan1(const int* __restrict__ counts, int* __restrict__ part,
                        int* __restrict__ blksum, int n1) {
    __shared__ int tmp[1024];
    int b = blockIdx.x, t = threadIdx.x, i = b * 1024 + t;
    int v = (i < n1) ? counts[i] : 0;
    tmp[t] = v;
    __syncthreads();
    for (int off = 1; off < 1024; off <<= 1) {
        int a = (t >= off) ? tmp[t - off] : 0;
        __syncthreads();
        tmp[t] += a;
        __syncthreads();
    }
    if (i < n1) part[i] = tmp[t];
    if (t == 1023) blksum[b] = tmp[t];
}

__global__ void k_scan2(int* __restrict__ blksum, int nb) {
    __shared__ int tmp[1024];
    int t = threadIdx.x;
    int v = (t < nb) ? blksum[t] : 0;
    tmp[t] = v;
    __syncthreads();
    for (int off = 1; off < 1024; off <<= 1) {
        int a = (t >= off) ? tmp[t - off] : 0;
        __syncthreads();
        tmp[t] += a;
        __syncthreads();
    }
    if (t < nb) blksum[t] = tmp[t];
}

__global__ void k_scan3(const int* __restrict__ blksum, int* __restrict__ row_ptr,
                        int* __restrict__ cursor, int n1) {
    int i = blockIdx.x * blockDim.x + threadIdx.x;
    if (i < n1) {
        int b = i >> 10;
        int off = (b > 0) ? blksum[b - 1] : 0;
        int v = row_ptr[i] + off;
        row_ptr[i] = v;
        cursor[i] = v;
    }
}

__global__ void k_scatter(const int* __restrict__ rows, const int* __restrict__ cols,
                          const float* __restrict__ vals, int* __restrict__ cursor,
                          int* __restrict__ cols_s, float* __restrict__ vals_s, int E) {
    int e = blockIdx.x * blockDim.x + threadIdx.x;
    if (e < E) {
        int r = rows[e];
        int pos = atomicAdd(&cursor[r], 1);
        cols_s[pos] = cols[e];
        vals_s[pos] = vals[e];
    }
}

// ---------------- degree counting-sort: perm groups rows of equal degree ----------
__global__ void k_dhist(const int* __restrict__ row_ptr, int* __restrict__ dbins, int N) {
    int i = blockIdx.x * blockDim.x + threadIdx.x;
    if (i < N) {
        int d = row_ptr[i + 1] - row_ptr[i];
        if (d > 63) d = 63;
        atomicAdd(&dbins[d], 1);
    }
}

__global__ void k_dscan(int* __restrict__ dbins) {   // 1 block, 64 threads
    __shared__ int tmp[64];
    int t = threadIdx.x;
    tmp[t] = dbins[t];
    __syncthreads();
    if (t == 0) {
        int acc = 0;
        for (int i = 0; i < 64; i++) { int v = tmp[i]; tmp[i] = acc; acc += v; }
    }
    __syncthreads();
    dbins[t] = tmp[t];   // exclusive scan -> scatter cursors
}

__global__ void k_dscatter(const int* __restrict__ row_ptr, int* __restrict__ dcursor,
                           int* __restrict__ perm, int N) {
    int i = blockIdx.x * blockDim.x + threadIdx.x;
    if (i < N) {
        int d = row_ptr[i + 1] - row_ptr[i];
        if (d > 63) d = 63;
        int pos = atomicAdd(&dcursor[d], 1);
        perm[pos] = i;
    }
}

// ---------------- M = (W*clip(d))@W^T - I, packed in MFMA B-fragment order ----------------
__global__ void k_build_m(const float* __restrict__ W, const float* __restrict__ dvec,
                          uint16_t* __restrict__ Mpk) {
    __shared__ float u[DD];
    int n = blockIdx.x, k = threadIdx.x;
    float dj = dvec[k];
    dj = fminf(fmaxf(dj, 0.f), 1.f);
    u[k] = W[n * DD + k] * dj;
    __syncthreads();
    float acc = 0.f;
    for (int j = 0; j < DD; j++) acc += u[j] * W[k * DD + j];
    acc -= (n == k) ? 1.f : 0.f;
    int tile = n >> 4, m = n & 15, kt = k >> 5, quad = (k >> 3) & 3, j = k & 7;
    int lane = quad * 16 + m;
    Mpk[(((tile * 8 + kt) * 64 + lane) << 3) + j] = (uint16_t)f2bf(acc);
}

// ---------------- init: znb = bf16([x,0]), xb = bf16(x), alpha = alpha0 ----------------
__global__ void k_init(const float* __restrict__ x, const float* __restrict__ alpha0,
                       uint16_t* __restrict__ znb, uint16_t* __restrict__ xb,
                       float* __restrict__ alpha, int N) {
    int idx = blockIdx.x * blockDim.x + threadIdx.x;
    int total = N * 64;
    if (idx < total) {
        int row = idx >> 6, c4 = idx & 63;
        float4 v = make_float4(0.f, 0.f, 0.f, 0.f);
        if (c4 < 32) v = ((const float4*)x)[(size_t)row * 32 + c4];
        ushort4 b;
        b.x = (uint16_t)f2bf(v.x); b.y = (uint16_t)f2bf(v.y);
        b.z = (uint16_t)f2bf(v.z); b.w = (uint16_t)f2bf(v.w);
        ((ushort4*)znb)[idx] = b;
        if (c4 < 32) ((ushort4*)xb)[(size_t)row * 32 + c4] = b;
    }
    if (idx < N) alpha[idx] = alpha0[idx];
}

// ---------------- fused eval (R8 phase order + degree-sorted row assignment) -------
// Block = 512 threads (8 waves), 16 rows = perm[16b..16b+15] (equal-degree group:
// block barrier no longer waits on a Poisson max). Wave w gathers/combines rows
// perm[16b+2w], perm[16b+2w+1]; MFMA col-tiles 2w,2w+1 for all 16 rows.
// az stays in f32 registers.
// f = alph*(az - z) + z@M + x0
// mode 0: zout = bf16(z + c1*f)
// mode 1: z2f = znb + c1*f; zout = bf16(z2f); Pout = bf16(z + 2*z2f - 3*znb)
// mode 2: zout = bf16(znb + c1*f)
// mode 3: znew = znb + (P + z - znb)/3 + c2*f; zout = bf16(znew)
// mode 4: same as 3 but f32 out (first 128 cols), no zout
// Aliasing: zout never aliases zsrc. In mode 3 zout==znb, but each actual row
// appears exactly once in perm and is only touched by its owning wave.
__global__ __launch_bounds__(512, 6) void k_fused(
    const uint16_t* zsrc, const uint16_t* znb, uint16_t* zout,
    uint16_t* __restrict__ Pout, const uint16_t* __restrict__ Pin,
    float* __restrict__ out,
    const uint16_t* __restrict__ Mpk, const uint16_t* __restrict__ xb,
    const int* __restrict__ perm,
    const int* __restrict__ row_ptr, const int* __restrict__ cols_s,
    const float* __restrict__ vals_s,
    const float* __restrict__ W_ih, const float* __restrict__ W_hh,
    const float* __restrict__ b_ih, const float* __restrict__ b_hh,
    const float* __restrict__ hbuf, float* __restrict__ alpha,
    int N, int mode, float c1, float c2)
{
    __shared__ uint16_t gs[16][264];   // z@M result, bf16  ~8.4 KB

    int t = threadIdx.x;
    int wv = t >> 6;            // 0..7
    int lane = t & 63;
    int r0 = blockIdx.x * 16;

    int row0 = wv * 2, row1 = wv * 2 + 1;
    int i0 = r0 + row0, i1 = r0 + row1;
    bool ok0 = i0 < N, ok1 = i1 < N;
    int g0 = ok0 ? perm[i0] : 0;
    int g1 = ok1 ? perm[i1] : 0;

    // own-row eval points (cols 4*lane..+3)
    ushort4 zr0 = ok0 ? ((const ushort4*)zsrc)[(size_t)g0 * 64 + lane] : make_ushort4(0,0,0,0);
    ushort4 zr1 = ok1 ? ((const ushort4*)zsrc)[(size_t)g1 * 64 + lane] : make_ushort4(0,0,0,0);

    // ---- gather both rows (az in f32 regs), interleaved chunk-4 ----
    int s0e = ok0 ? row_ptr[g0] : 0, e0e = ok0 ? row_ptr[g0 + 1] : 0;
    int s1e = ok1 ? row_ptr[g1] : 0, e1e = ok1 ? row_ptr[g1 + 1] : 0;
    int d0 = e0e - s0e, d1 = e1e - s1e;
    int dmax = (d0 > d1) ? d0 : d1;
    float4 az0 = make_float4(0.f, 0.f, 0.f, 0.f);
    float4 az1 = make_float4(0.f, 0.f, 0.f, 0.f);
    for (int i = 0; i < dmax; i += 4) {
        if (i < d0) {
            int rem = d0 - i, base = s0e + i;
            int ca = cols_s[base];
            float va = vals_s[base];
            int cb = 0, cc = 0, cd = 0;
            float vb = 0.f, vc = 0.f, vd = 0.f;
            if (rem > 1) { cb = cols_s[base + 1]; vb = vals_s[base + 1]; }
            if (rem > 2) { cc = cols_s[base + 2]; vc = vals_s[base + 2]; }
            if (rem > 3) { cd = cols_s[base + 3]; vd = vals_s[base + 3]; }
            ushort4 ra = ((const ushort4*)zsrc)[(size_t)ca * 64 + lane];
            ushort4 rb = (rem > 1) ? ((const ushort4*)zsrc)[(size_t)cb * 64 + lane] : make_ushort4(0,0,0,0);
            ushort4 rc = (rem > 2) ? ((const ushort4*)zsrc)[(size_t)cc * 64 + lane] : make_ushort4(0,0,0,0);
            ushort4 rd = (rem > 3) ? ((const ushort4*)zsrc)[(size_t)cd * 64 + lane] : make_ushort4(0,0,0,0);
            az0.x += va * bf2f(ra.x) + vb * bf2f(rb.x) + vc * bf2f(rc.x) + vd * bf2f(rd.x);
            az0.y += va * bf2f(ra.y) + vb * bf2f(rb.y) + vc * bf2f(rc.y) + vd * bf2f(rd.y);
            az0.z += va * bf2f(ra.z) + vb * bf2f(rb.z) + vc * bf2f(rc.z) + vd * bf2f(rd.z);
            az0.w += va * bf2f(ra.w) + vb * bf2f(rb.w) + vc * bf2f(rc.w) + vd * bf2f(rd.w);
        }
        if (i < d1) {
            int rem = d1 - i, base = s1e + i;
            int ca = cols_s[base];
            float va = vals_s[base];
            int cb = 0, cc = 0, cd = 0;
            float vb = 0.f, vc = 0.f, vd = 0.f;
            if (rem > 1) { cb = cols_s[base + 1]; vb = vals_s[base + 1]; }
            if (rem > 2) { cc = cols_s[base + 2]; vc = vals_s[base + 2]; }
            if (rem > 3) { cd = cols_s[base + 3]; vd = vals_s[base + 3]; }
            ushort4 ra = ((const ushort4*)zsrc)[(size_t)ca * 64 + lane];
            ushort4 rb = (rem > 1) ? ((const ushort4*)zsrc)[(size_t)cb * 64 + lane] : make_ushort4(0,0,0,0);
            ushort4 rc = (rem > 2) ? ((const ushort4*)zsrc)[(size_t)cc * 64 + lane] : make_ushort4(0,0,0,0);
            ushort4 rd = (rem > 3) ? ((const ushort4*)zsrc)[(size_t)cd * 64 + lane] : make_ushort4(0,0,0,0);
            az1.x += va * bf2f(ra.x) + vb * bf2f(rb.x) + vc * bf2f(rc.x) + vd * bf2f(rd.x);
            az1.y += va * bf2f(ra.y) + vb * bf2f(rb.y) + vc * bf2f(rc.y) + vd * bf2f(rd.y);
            az1.z += va * bf2f(ra.z) + vb * bf2f(rb.z) + vc * bf2f(rc.z) + vd * bf2f(rd.z);
            az1.w += va * bf2f(ra.w) + vb * bf2f(rb.w) + vc * bf2f(rc.w) + vd * bf2f(rd.w);
        }
    }

    // ---- MFMA: col tiles 2w, 2w+1 over all 16 block rows ----
    int m = lane & 15, quad = lane >> 4;
    int t0 = wv * 2, t1 = wv * 2 + 1;
    int ia = r0 + m;
    bool aok = ia < N;
    int arow_g = aok ? perm[ia] : 0;
    f32x4 acc0 = {0.f, 0.f, 0.f, 0.f};
    f32x4 acc1 = {0.f, 0.f, 0.f, 0.f};
    #pragma unroll
    for (int kt = 0; kt < 8; kt++) {
        short8 a = aok ? *(const short8*)(zsrc + (size_t)arow_g * 256 + kt * 32 + quad * 8)
                       : short8{0, 0, 0, 0, 0, 0, 0, 0};
        short8 b0 = ((const short8*)Mpk)[(t0 * 8 + kt) * 64 + lane];
        short8 b1 = ((const short8*)Mpk)[(t1 * 8 + kt) * 64 + lane];
        acc0 = __builtin_amdgcn_mfma_f32_16x16x32_bf16(a, b0, acc0, 0, 0, 0);
        acc1 = __builtin_amdgcn_mfma_f32_16x16x32_bf16(a, b1, acc1, 0, 0, 0);
    }
    // C layout: col = lane&15, row = quad*4 + r
    #pragma unroll
    for (int r = 0; r < 4; r++) {
        gs[quad * 4 + r][t0 * 16 + m] = (uint16_t)f2bf(acc0[r]);
        gs[quad * 4 + r][t1 * 16 + m] = (uint16_t)f2bf(acc1[r]);
    }

    // ---- alpha RNN update for both rows (while MFMA stores settle) ----
    float4 wih0 = ((const float4*)W_ih)[lane];
    float4 wih1 = ((const float4*)(W_ih + DD))[lane];
    float z00 = bf2f(zr0.x), z01 = bf2f(zr0.y), z02 = bf2f(zr0.z), z03 = bf2f(zr0.w);
    float z10 = bf2f(zr1.x), z11 = bf2f(zr1.y), z12 = bf2f(zr1.z), z13 = bf2f(zr1.w);
    float s00 = z00 * wih0.x + z01 * wih0.y + z02 * wih0.z + z03 * wih0.w;
    float s01 = z00 * wih1.x + z01 * wih1.y + z02 * wih1.z + z03 * wih1.w;
    float s10 = z10 * wih0.x + z11 * wih0.y + z12 * wih0.z + z13 * wih0.w;
    float s11 = z10 * wih1.x + z11 * wih1.y + z12 * wih1.z + z13 * wih1.w;
    #pragma unroll
    for (int off = 32; off >= 1; off >>= 1) {
        s00 += __shfl_down(s00, off, 64);
        s01 += __shfl_down(s01, off, 64);
        s10 += __shfl_down(s10, off, 64);
        s11 += __shfl_down(s11, off, 64);
    }
    float alph0 = 0.f, alph1 = 0.f;
    if (lane == 0) {
        float bi0 = b_ih[0] + b_hh[0], bi1 = b_ih[1] + b_hh[1];
        float wh0 = W_hh[0], wh1 = W_hh[1], wh2 = W_hh[2], wh3 = W_hh[3];
        if (ok0) {
            float h0 = hbuf[g0 * 2], h1 = hbuf[g0 * 2 + 1];
            float anew = alpha[g0] * tanhf(s00 + bi0 + h0 * wh0 + h1 * wh1)
                       + tanhf(s01 + bi1 + h0 * wh2 + h1 * wh3);
            alpha[g0] = anew;
            alph0 = 0.5f / (1.f + expf(-anew));
        }
        if (ok1) {
            float h0 = hbuf[g1 * 2], h1 = hbuf[g1 * 2 + 1];
            float anew = alpha[g1] * tanhf(s10 + bi0 + h0 * wh0 + h1 * wh1)
                       + tanhf(s11 + bi1 + h0 * wh2 + h1 * wh3);
            alpha[g1] = anew;
            alph1 = 0.5f / (1.f + expf(-anew));
        }
    }
    alph0 = __shfl(alph0, 0, 64);
    alph1 = __shfl(alph1, 0, 64);

    __syncthreads();

    // ---- combine + RK4 for this wave's two rows ----
    #pragma unroll
    for (int rr = 0; rr < 2; rr++) {
        int rowloc = (rr == 0) ? row0 : row1;
        int grow = (rr == 0) ? g0 : g1;
        bool ok = (rr == 0) ? ok0 : ok1;
        if (!ok) continue;
        float4 azv = (rr == 0) ? az0 : az1;
        ushort4 z4 = (rr == 0) ? zr0 : zr1;
        float al = (rr == 0) ? alph0 : alph1;
        size_t b4 = (size_t)grow * 64 + lane;
        ushort4 g4 = *(const ushort4*)&gs[rowloc][lane * 4];
        float4 x4 = make_float4(0.f, 0.f, 0.f, 0.f);
        if (lane < 32) {
            ushort4 v = ((const ushort4*)xb)[(size_t)grow * 32 + lane];
            x4.x = bf2f(v.x); x4.y = bf2f(v.y); x4.z = bf2f(v.z); x4.w = bf2f(v.w);
        }
        float zv0 = bf2f(z4.x), zv1 = bf2f(z4.y), zv2 = bf2f(z4.z), zv3 = bf2f(z4.w);
        float f0 = al * (azv.x - zv0) + bf2f(g4.x) + x4.x;
        float f1 = al * (azv.y - zv1) + bf2f(g4.y) + x4.y;
        float f2 = al * (azv.z - zv2) + bf2f(g4.z) + x4.z;
        float f3 = al * (azv.w - zv3) + bf2f(g4.w) + x4.w;
        if (mode == 0) {
            ushort4 o;
            o.x = (uint16_t)f2bf(zv0 + c1 * f0); o.y = (uint16_t)f2bf(zv1 + c1 * f1);
            o.z = (uint16_t)f2bf(zv2 + c1 * f2); o.w = (uint16_t)f2bf(zv3 + c1 * f3);
            ((ushort4*)zout)[b4] = o;
        } else if (mode == 1) {
            ushort4 zb = ((const ushort4*)znb)[b4];
            float zb0 = bf2f(zb.x), zb1 = bf2f(zb.y), zb2 = bf2f(zb.z), zb3 = bf2f(zb.w);
            float z20 = zb0 + c1 * f0, z21 = zb1 + c1 * f1;
            float z22 = zb2 + c1 * f2, z23 = zb3 + c1 * f3;
            ushort4 o, p;
            o.x = (uint16_t)f2bf(z20); o.y = (uint16_t)f2bf(z21);
            o.z = (uint16_t)f2bf(z22); o.w = (uint16_t)f2bf(z23);
            p.x = (uint16_t)f2bf(zv0 + 2.f * z20 - 3.f * zb0);
            p.y = (uint16_t)f2bf(zv1 + 2.f * z21 - 3.f * zb1);
            p.z = (uint16_t)f2bf(zv2 + 2.f * z22 - 3.f * zb2);
            p.w = (uint16_t)f2bf(zv3 + 2.f * z23 - 3.f * zb3);
            ((ushort4*)zout)[b4] = o;
            ((ushort4*)Pout)[b4] = p;
        } else if (mode == 2) {
            ushort4 zb = ((const ushort4*)znb)[b4];
            ushort4 o;
            o.x = (uint16_t)f2bf(bf2f(zb.x) + c1 * f0);
            o.y = (uint16_t)f2bf(bf2f(zb.y) + c1 * f1);
            o.z = (uint16_t)f2bf(bf2f(zb.z) + c1 * f2);
            o.w = (uint16_t)f2bf(bf2f(zb.w) + c1 * f3);
            ((ushort4*)zout)[b4] = o;
        } else {
            // znew = znb + (P + z3 - znb)/3 + c2*f
            ushort4 zb = ((const ushort4*)znb)[b4];
            ushort4 p4 = ((const ushort4*)Pin)[b4];
            const float third = 1.f / 3.f;
            float zb0 = bf2f(zb.x), zb1 = bf2f(zb.y), zb2 = bf2f(zb.z), zb3 = bf2f(zb.w);
            float r0v = zb0 + (bf2f(p4.x) + zv0 - zb0) * third + c2 * f0;
            float r1v = zb1 + (bf2f(p4.y) + zv1 - zb1) * third + c2 * f1;
            float r2v = zb2 + (bf2f(p4.z) + zv2 - zb2) * third + c2 * f2;
            float r3v = zb3 + (bf2f(p4.w) + zv3 - zb3) * third + c2 * f3;
            if (mode == 3) {
                ushort4 o;
                o.x = (uint16_t)f2bf(r0v); o.y = (uint16_t)f2bf(r1v);
                o.z = (uint16_t)f2bf(r2v); o.w = (uint16_t)f2bf(r3v);
                ((ushort4*)zout)[b4] = o;
            } else {
                if (lane < 32) {
                    float4 o;
                    o.x = r0v; o.y = r1v; o.z = r2v; o.w = r3v;
                    ((float4*)out)[(size_t)grow * 32 + lane] = o;
                }
            }
        }
    }
}

__global__ void k_fill(float* __restrict__ out, int n, float v) {
    int idx = blockIdx.x * blockDim.x + threadIdx.x;
    if (idx < n) out[idx] = v;
}

static inline size_t alignup(size_t v) { return (v + 255) & ~(size_t)255; }

extern "C" void kernel_launch(void* const* d_in, const int* in_sizes, int n_in,
                              void* d_out, int out_size, void* d_ws, size_t ws_size,
                              hipStream_t stream) {
    const float* x      = (const float*)d_in[0];
    const int*   erow   = (const int*)d_in[1];
    const int*   ecol   = (const int*)d_in[2];
    const float* evals  = (const float*)d_in[3];
    const float* W_ih   = (const float*)d_in[4];
    const float* W_hh   = (const float*)d_in[5];
    const float* b_ih   = (const float*)d_in[6];
    const float* b_hh   = (const float*)d_in[7];
    const float* h      = (const float*)d_in[8];
    const float* alpha0 = (const float*)d_in[9];
    const float* W      = (const float*)d_in[10];
    const float* dvec   = (const float*)d_in[11];

    int N = in_sizes[0] / DINF;
    int E = in_sizes[1];

    char* w = (char*)d_ws;
    uint16_t* znb = (uint16_t*)w; w += alignup((size_t)N * DD * 2);   //  51.2 MB
    uint16_t* B1  = (uint16_t*)w; w += alignup((size_t)N * DD * 2);   //  51.2 MB (z1 / z3)
    uint16_t* P   = (uint16_t*)w; w += alignup((size_t)N * DD * 2);   //  51.2 MB (D-fold)
    uint16_t* xb  = (uint16_t*)w; w += alignup((size_t)N * DINF * 2); //  25.6 MB
    float* alpha = (float*)w;     w += alignup((size_t)N * 4);
    uint16_t* Mpk = (uint16_t*)w; w += alignup((size_t)DD * DD * 2);
    int* counts = (int*)w;        w += alignup((size_t)(N + 1) * 4);  // reused as cursor
    int* row_ptr = (int*)w;       w += alignup((size_t)(N + 1) * 4);
    int* blksum = (int*)w;        w += alignup((size_t)1024 * 4);
    int* cols_s = (int*)w;        w += alignup((size_t)E * 4);
    float* vals_s = (float*)w;    w += alignup((size_t)E * 4);
    int* perm = (int*)w;          w += alignup((size_t)N * 4);        // degree-sorted rows
    int* dbins = (int*)w;         w += alignup((size_t)64 * 4);
    size_t need = (size_t)(w - (char*)d_ws);   // ~188 MB

    // B2 (z2) lives in d_out (N*128 f32 = N*256 bf16 exactly); dead after eval3's
    // gather; final mode-4 eval overwrites d_out with the fp32 result.
    uint16_t* B2 = (uint16_t*)d_out;

    if (ws_size < need) {
        k_fill<<<(out_size + 255) / 256, 256, 0, stream>>>((float*)d_out, out_size, 1000.0f);
        return;
    }

    int n1 = N + 1, nb = (n1 + 1023) / 1024;
    hipMemsetAsync(counts, 0, (size_t)n1 * 4, stream);
    k_hist<<<(E + 255) / 256, 256, 0, stream>>>(erow, counts, E);
    k_scan1<<<nb, 1024, 0, stream>>>(counts, row_ptr, blksum, n1);
    k_scan2<<<1, 1024, 0, stream>>>(blksum, nb);
    k_scan3<<<(n1 + 255) / 256, 256, 0, stream>>>(blksum, row_ptr, counts, n1);
    k_scatter<<<(E + 255) / 256, 256, 0, stream>>>(erow, ecol, evals, counts, cols_s, vals_s, E);

    // degree counting-sort -> perm (equal-degree blocks for k_fused)
    hipMemsetAsync(dbins, 0, 64 * 4, stream);
    k_dhist<<<(N + 255) / 256, 256, 0, stream>>>(row_ptr, dbins, N);
    k_dscan<<<1, 64, 0, stream>>>(dbins);
    k_dscatter<<<(N + 255) / 256, 256, 0, stream>>>(row_ptr, dbins, perm, N);

    k_build_m<<<DD, DD, 0, stream>>>(W, dvec, Mpk);
    k_init<<<(N * 64 + 255) / 256, 256, 0, stream>>>(x, alpha0, znb, xb, alpha, N);

    const float dt = 0.45f;  // T_END / N_STEPS
    int ge = (N + 15) / 16;
    for (int s = 0; s < 2; s++) {
        // eval1: znb -> z1 (B1)
        k_fused<<<ge, 512, 0, stream>>>(znb, znb, B1, nullptr, nullptr, nullptr,
                                        Mpk, xb, perm, row_ptr, cols_s, vals_s,
                                        W_ih, W_hh, b_ih, b_hh, h, alpha,
                                        N, 0, 0.5f * dt, 0.f);
        // eval2: z1 (B1) -> z2 (B2=d_out), D -> P
        k_fused<<<ge, 512, 0, stream>>>(B1, znb, B2, P, nullptr, nullptr,
                                        Mpk, xb, perm, row_ptr, cols_s, vals_s,
                                        W_ih, W_hh, b_ih, b_hh, h, alpha,
                                        N, 1, 0.5f * dt, 0.f);
        // eval3: z2 (B2) -> z3 (B1)
        k_fused<<<ge, 512, 0, stream>>>(B2, znb, B1, nullptr, nullptr, nullptr,
                                        Mpk, xb, perm, row_ptr, cols_s, vals_s,
                                        W_ih, W_hh, b_ih, b_hh, h, alpha,
                                        N, 2, dt, 0.f);
        // eval4: z3 (B1) -> znew
        if (s == 0) {
            k_fused<<<ge, 512, 0, stream>>>(B1, znb, znb, nullptr, P, nullptr,
                                            Mpk, xb, perm, row_ptr, cols_s, vals_s,
                                            W_ih, W_hh, b_ih, b_hh, h, alpha,
                                            N, 3, 0.f, dt / 6.f);
        } else {
            // final: emit fp32 output directly (first 128 cols)
            k_fused<<<ge, 512, 0, stream>>>(B1, znb, nullptr, nullptr, P,
                                            (float*)d_out,
                                            Mpk, xb, perm, row_ptr, cols_s, vals_s,
                                            W_ih, W_hh, b_ih, b_hh, h, alpha,
                                            N, 4, 0.f, dt / 6.f);
        }
    }
}

// Round 12
// 1424.399 us; speedup vs baseline: 1.4797x; 1.4797x over previous
//
#include <hip/hip_runtime.h>
#include <stdint.h>

#define DD 256
#define DINF 128

typedef __attribute__((ext_vector_type(8))) short short8;
typedef __attribute__((ext_vector_type(4))) float f32x4;

__device__ __forceinline__ short f2bf(float f) {
    union { float f; uint32_t u; } c{f};
    uint32_t r = (c.u + 0x7fffu + ((c.u >> 16) & 1u)) >> 16;
    return (short)(uint16_t)r;
}

__device__ __forceinline__ float bf2f(uint16_t b) {
    union { uint32_t u; float f; } c;
    c.u = ((uint32_t)b) << 16;
    return c.f;
}

// ---------------- CSR build ----------------
__global__ void k_hist(const int* __restrict__ rows, int* __restrict__ counts, int E) {
    int e = blockIdx.x * blockDim.x + threadIdx.x;
    if (e < E) atomicAdd(&counts[rows[e] + 1], 1);
}

__global__ void k_scan1(const int* __restrict__ counts, int* __restrict__ part,
                        int* __restrict__ blksum, int n1) {
    __shared__ int tmp[1024];
    int b = blockIdx.x, t = threadIdx.x, i = b * 1024 + t;
    int v = (i < n1) ? counts[i] : 0;
    tmp[t] = v;
    __syncthreads();
    for (int off = 1; off < 1024; off <<= 1) {
        int a = (t >= off) ? tmp[t - off] : 0;
        __syncthreads();
        tmp[t] += a;
        __syncthreads();
    }
    if (i < n1) part[i] = tmp[t];
    if (t == 1023) blksum[b] = tmp[t];
}

__global__ void k_scan2(int* __restrict__ blksum, int nb) {
    __shared__ int tmp[1024];
    int t = threadIdx.x;
    int v = (t < nb) ? blksum[t] : 0;
    tmp[t] = v;
    __syncthreads();
    for (int off = 1; off < 1024; off <<= 1) {
        int a = (t >= off) ? tmp[t - off] : 0;
        __syncthreads();
        tmp[t] += a;
        __syncthreads();
    }
    if (t < nb) blksum[t] = tmp[t];
}

__global__ void k_scan3(const int* __restrict__ blksum, int* __restrict__ row_ptr,
                        int* __restrict__ cursor, int n1) {
    int i = blockIdx.x * blockDim.x + threadIdx.x;
    if (i < n1) {
        int b = i >> 10;
        int off = (b > 0) ? blksum[b - 1] : 0;
        int v = row_ptr[i] + off;
        row_ptr[i] = v;
        cursor[i] = v;
    }
}

__global__ void k_scatter(const int* __restrict__ rows, const int* __restrict__ cols,
                          const float* __restrict__ vals, int* __restrict__ cursor,
                          int* __restrict__ cols_s, float* __restrict__ vals_s, int E) {
    int e = blockIdx.x * blockDim.x + threadIdx.x;
    if (e < E) {
        int r = rows[e];
        int pos = atomicAdd(&cursor[r], 1);
        cols_s[pos] = cols[e];
        vals_s[pos] = vals[e];
    }
}

// ---------------- degree counting-sort (two-level atomics: LDS then global) -------
__global__ void k_dhist(const int* __restrict__ row_ptr, int* __restrict__ dbins, int N) {
    __shared__ int lbin[64];
    int t = threadIdx.x;
    if (t < 64) lbin[t] = 0;
    __syncthreads();
    int i = blockIdx.x * blockDim.x + t;
    if (i < N) {
        int d = row_ptr[i + 1] - row_ptr[i];
        if (d > 63) d = 63;
        atomicAdd(&lbin[d], 1);          // LDS atomic: intra-block only
    }
    __syncthreads();
    if (t < 64 && lbin[t] > 0) atomicAdd(&dbins[t], lbin[t]);  // 64 global adds/block
}

__global__ void k_dscan(int* __restrict__ dbins) {   // 1 block, 64 threads
    __shared__ int tmp[64];
    int t = threadIdx.x;
    tmp[t] = dbins[t];
    __syncthreads();
    if (t == 0) {
        int acc = 0;
        for (int i = 0; i < 64; i++) { int v = tmp[i]; tmp[i] = acc; acc += v; }
    }
    __syncthreads();
    dbins[t] = tmp[t];   // exclusive scan -> scatter cursors
}

__global__ void k_dscatter(const int* __restrict__ row_ptr, int* __restrict__ dcursor,
                           int* __restrict__ perm, int N) {
    __shared__ int lbin[64];
    __shared__ int lbase[64];
    int t = threadIdx.x;
    if (t < 64) lbin[t] = 0;
    __syncthreads();
    int i = blockIdx.x * blockDim.x + t;
    bool ok = i < N;
    int d = 0, lpos = 0;
    if (ok) {
        d = row_ptr[i + 1] - row_ptr[i];
        if (d > 63) d = 63;
        lpos = atomicAdd(&lbin[d], 1);   // LDS atomic: local position
    }
    __syncthreads();
    if (t < 64) lbase[t] = (lbin[t] > 0) ? atomicAdd(&dcursor[t], lbin[t]) : 0;
    __syncthreads();
    if (ok) perm[lbase[d] + lpos] = i;
}

// ---------------- M = (W*clip(d))@W^T - I, packed in MFMA B-fragment order ----------------
__global__ void k_build_m(const float* __restrict__ W, const float* __restrict__ dvec,
                          uint16_t* __restrict__ Mpk) {
    __shared__ float u[DD];
    int n = blockIdx.x, k = threadIdx.x;
    float dj = dvec[k];
    dj = fminf(fmaxf(dj, 0.f), 1.f);
    u[k] = W[n * DD + k] * dj;
    __syncthreads();
    float acc = 0.f;
    for (int j = 0; j < DD; j++) acc += u[j] * W[k * DD + j];
    acc -= (n == k) ? 1.f : 0.f;
    int tile = n >> 4, m = n & 15, kt = k >> 5, quad = (k >> 3) & 3, j = k & 7;
    int lane = quad * 16 + m;
    Mpk[(((tile * 8 + kt) * 64 + lane) << 3) + j] = (uint16_t)f2bf(acc);
}

// ---------------- init: znb = bf16([x,0]), xb = bf16(x), alpha = alpha0 ----------------
__global__ void k_init(const float* __restrict__ x, const float* __restrict__ alpha0,
                       uint16_t* __restrict__ znb, uint16_t* __restrict__ xb,
                       float* __restrict__ alpha, int N) {
    int idx = blockIdx.x * blockDim.x + threadIdx.x;
    int total = N * 64;
    if (idx < total) {
        int row = idx >> 6, c4 = idx & 63;
        float4 v = make_float4(0.f, 0.f, 0.f, 0.f);
        if (c4 < 32) v = ((const float4*)x)[(size_t)row * 32 + c4];
        ushort4 b;
        b.x = (uint16_t)f2bf(v.x); b.y = (uint16_t)f2bf(v.y);
        b.z = (uint16_t)f2bf(v.z); b.w = (uint16_t)f2bf(v.w);
        ((ushort4*)znb)[idx] = b;
        if (c4 < 32) ((ushort4*)xb)[(size_t)row * 32 + c4] = b;
    }
    if (idx < N) alpha[idx] = alpha0[idx];
}

// ---------------- fused eval (R8 phase order + degree-sorted row assignment) -------
// Block = 512 threads (8 waves), 16 rows = perm[16b..16b+15] (equal-degree group:
// block barrier no longer waits on a Poisson max). Wave w gathers/combines rows
// perm[16b+2w], perm[16b+2w+1]; MFMA col-tiles 2w,2w+1 for all 16 rows.
// az stays in f32 registers.
// f = alph*(az - z) + z@M + x0
// mode 0: zout = bf16(z + c1*f)
// mode 1: z2f = znb + c1*f; zout = bf16(z2f); Pout = bf16(z + 2*z2f - 3*znb)
// mode 2: zout = bf16(znb + c1*f)
// mode 3: znew = znb + (P + z - znb)/3 + c2*f; zout = bf16(znew)
// mode 4: same as 3 but f32 out (first 128 cols), no zout
__global__ __launch_bounds__(512, 6) void k_fused(
    const uint16_t* zsrc, const uint16_t* znb, uint16_t* zout,
    uint16_t* __restrict__ Pout, const uint16_t* __restrict__ Pin,
    float* __restrict__ out,
    const uint16_t* __restrict__ Mpk, const uint16_t* __restrict__ xb,
    const int* __restrict__ perm,
    const int* __restrict__ row_ptr, const int* __restrict__ cols_s,
    const float* __restrict__ vals_s,
    const float* __restrict__ W_ih, const float* __restrict__ W_hh,
    const float* __restrict__ b_ih, const float* __restrict__ b_hh,
    const float* __restrict__ hbuf, float* __restrict__ alpha,
    int N, int mode, float c1, float c2)
{
    __shared__ uint16_t gs[16][264];   // z@M result, bf16  ~8.4 KB

    int t = threadIdx.x;
    int wv = t >> 6;            // 0..7
    int lane = t & 63;
    int r0 = blockIdx.x * 16;

    int row0 = wv * 2, row1 = wv * 2 + 1;
    int i0 = r0 + row0, i1 = r0 + row1;
    bool ok0 = i0 < N, ok1 = i1 < N;
    int g0 = ok0 ? perm[i0] : 0;
    int g1 = ok1 ? perm[i1] : 0;

    // own-row eval points (cols 4*lane..+3)
    ushort4 zr0 = ok0 ? ((const ushort4*)zsrc)[(size_t)g0 * 64 + lane] : make_ushort4(0,0,0,0);
    ushort4 zr1 = ok1 ? ((const ushort4*)zsrc)[(size_t)g1 * 64 + lane] : make_ushort4(0,0,0,0);

    // ---- gather both rows (az in f32 regs), interleaved chunk-4 ----
    int s0e = ok0 ? row_ptr[g0] : 0, e0e = ok0 ? row_ptr[g0 + 1] : 0;
    int s1e = ok1 ? row_ptr[g1] : 0, e1e = ok1 ? row_ptr[g1 + 1] : 0;
    int d0 = e0e - s0e, d1 = e1e - s1e;
    int dmax = (d0 > d1) ? d0 : d1;
    float4 az0 = make_float4(0.f, 0.f, 0.f, 0.f);
    float4 az1 = make_float4(0.f, 0.f, 0.f, 0.f);
    for (int i = 0; i < dmax; i += 4) {
        if (i < d0) {
            int rem = d0 - i, base = s0e + i;
            int ca = cols_s[base];
            float va = vals_s[base];
            int cb = 0, cc = 0, cd = 0;
            float vb = 0.f, vc = 0.f, vd = 0.f;
            if (rem > 1) { cb = cols_s[base + 1]; vb = vals_s[base + 1]; }
            if (rem > 2) { cc = cols_s[base + 2]; vc = vals_s[base + 2]; }
            if (rem > 3) { cd = cols_s[base + 3]; vd = vals_s[base + 3]; }
            ushort4 ra = ((const ushort4*)zsrc)[(size_t)ca * 64 + lane];
            ushort4 rb = (rem > 1) ? ((const ushort4*)zsrc)[(size_t)cb * 64 + lane] : make_ushort4(0,0,0,0);
            ushort4 rc = (rem > 2) ? ((const ushort4*)zsrc)[(size_t)cc * 64 + lane] : make_ushort4(0,0,0,0);
            ushort4 rd = (rem > 3) ? ((const ushort4*)zsrc)[(size_t)cd * 64 + lane] : make_ushort4(0,0,0,0);
            az0.x += va * bf2f(ra.x) + vb * bf2f(rb.x) + vc * bf2f(rc.x) + vd * bf2f(rd.x);
            az0.y += va * bf2f(ra.y) + vb * bf2f(rb.y) + vc * bf2f(rc.y) + vd * bf2f(rd.y);
            az0.z += va * bf2f(ra.z) + vb * bf2f(rb.z) + vc * bf2f(rc.z) + vd * bf2f(rd.z);
            az0.w += va * bf2f(ra.w) + vb * bf2f(rb.w) + vc * bf2f(rc.w) + vd * bf2f(rd.w);
        }
        if (i < d1) {
            int rem = d1 - i, base = s1e + i;
            int ca = cols_s[base];
            float va = vals_s[base];
            int cb = 0, cc = 0, cd = 0;
            float vb = 0.f, vc = 0.f, vd = 0.f;
            if (rem > 1) { cb = cols_s[base + 1]; vb = vals_s[base + 1]; }
            if (rem > 2) { cc = cols_s[base + 2]; vc = vals_s[base + 2]; }
            if (rem > 3) { cd = cols_s[base + 3]; vd = vals_s[base + 3]; }
            ushort4 ra = ((const ushort4*)zsrc)[(size_t)ca * 64 + lane];
            ushort4 rb = (rem > 1) ? ((const ushort4*)zsrc)[(size_t)cb * 64 + lane] : make_ushort4(0,0,0,0);
            ushort4 rc = (rem > 2) ? ((const ushort4*)zsrc)[(size_t)cc * 64 + lane] : make_ushort4(0,0,0,0);
            ushort4 rd = (rem > 3) ? ((const ushort4*)zsrc)[(size_t)cd * 64 + lane] : make_ushort4(0,0,0,0);
            az1.x += va * bf2f(ra.x) + vb * bf2f(rb.x) + vc * bf2f(rc.x) + vd * bf2f(rd.x);
            az1.y += va * bf2f(ra.y) + vb * bf2f(rb.y) + vc * bf2f(rc.y) + vd * bf2f(rd.y);
            az1.z += va * bf2f(ra.z) + vb * bf2f(rb.z) + vc * bf2f(rc.z) + vd * bf2f(rd.z);
            az1.w += va * bf2f(ra.w) + vb * bf2f(rb.w) + vc * bf2f(rc.w) + vd * bf2f(rd.w);
        }
    }

    // ---- MFMA: col tiles 2w, 2w+1 over all 16 block rows ----
    int m = lane & 15, quad = lane >> 4;
    int t0 = wv * 2, t1 = wv * 2 + 1;
    int ia = r0 + m;
    bool aok = ia < N;
    int arow_g = aok ? perm[ia] : 0;
    f32x4 acc0 = {0.f, 0.f, 0.f, 0.f};
    f32x4 acc1 = {0.f, 0.f, 0.f, 0.f};
    #pragma unroll
    for (int kt = 0; kt < 8; kt++) {
        short8 a = aok ? *(const short8*)(zsrc + (size_t)arow_g * 256 + kt * 32 + quad * 8)
                       : short8{0, 0, 0, 0, 0, 0, 0, 0};
        short8 b0 = ((const short8*)Mpk)[(t0 * 8 + kt) * 64 + lane];
        short8 b1 = ((const short8*)Mpk)[(t1 * 8 + kt) * 64 + lane];
        acc0 = __builtin_amdgcn_mfma_f32_16x16x32_bf16(a, b0, acc0, 0, 0, 0);
        acc1 = __builtin_amdgcn_mfma_f32_16x16x32_bf16(a, b1, acc1, 0, 0, 0);
    }
    // C layout: col = lane&15, row = quad*4 + r
    #pragma unroll
    for (int r = 0; r < 4; r++) {
        gs[quad * 4 + r][t0 * 16 + m] = (uint16_t)f2bf(acc0[r]);
        gs[quad * 4 + r][t1 * 16 + m] = (uint16_t)f2bf(acc1[r]);
    }

    // ---- alpha RNN update for both rows (while MFMA stores settle) ----
    float4 wih0 = ((const float4*)W_ih)[lane];
    float4 wih1 = ((const float4*)(W_ih + DD))[lane];
    float z00 = bf2f(zr0.x), z01 = bf2f(zr0.y), z02 = bf2f(zr0.z), z03 = bf2f(zr0.w);
    float z10 = bf2f(zr1.x), z11 = bf2f(zr1.y), z12 = bf2f(zr1.z), z13 = bf2f(zr1.w);
    float s00 = z00 * wih0.x + z01 * wih0.y + z02 * wih0.z + z03 * wih0.w;
    float s01 = z00 * wih1.x + z01 * wih1.y + z02 * wih1.z + z03 * wih1.w;
    float s10 = z10 * wih0.x + z11 * wih0.y + z12 * wih0.z + z13 * wih0.w;
    float s11 = z10 * wih1.x + z11 * wih1.y + z12 * wih1.z + z13 * wih1.w;
    #pragma unroll
    for (int off = 32; off >= 1; off >>= 1) {
        s00 += __shfl_down(s00, off, 64);
        s01 += __shfl_down(s01, off, 64);
        s10 += __shfl_down(s10, off, 64);
        s11 += __shfl_down(s11, off, 64);
    }
    float alph0 = 0.f, alph1 = 0.f;
    if (lane == 0) {
        float bi0 = b_ih[0] + b_hh[0], bi1 = b_ih[1] + b_hh[1];
        float wh0 = W_hh[0], wh1 = W_hh[1], wh2 = W_hh[2], wh3 = W_hh[3];
        if (ok0) {
            float h0 = hbuf[g0 * 2], h1 = hbuf[g0 * 2 + 1];
            float anew = alpha[g0] * tanhf(s00 + bi0 + h0 * wh0 + h1 * wh1)
                       + tanhf(s01 + bi1 + h0 * wh2 + h1 * wh3);
            alpha[g0] = anew;
            alph0 = 0.5f / (1.f + expf(-anew));
        }
        if (ok1) {
            float h0 = hbuf[g1 * 2], h1 = hbuf[g1 * 2 + 1];
            float anew = alpha[g1] * tanhf(s10 + bi0 + h0 * wh0 + h1 * wh1)
                       + tanhf(s11 + bi1 + h0 * wh2 + h1 * wh3);
            alpha[g1] = anew;
            alph1 = 0.5f / (1.f + expf(-anew));
        }
    }
    alph0 = __shfl(alph0, 0, 64);
    alph1 = __shfl(alph1, 0, 64);

    __syncthreads();

    // ---- combine + RK4 for this wave's two rows ----
    #pragma unroll
    for (int rr = 0; rr < 2; rr++) {
        int rowloc = (rr == 0) ? row0 : row1;
        int grow = (rr == 0) ? g0 : g1;
        bool ok = (rr == 0) ? ok0 : ok1;
        if (!ok) continue;
        float4 azv = (rr == 0) ? az0 : az1;
        ushort4 z4 = (rr == 0) ? zr0 : zr1;
        float al = (rr == 0) ? alph0 : alph1;
        size_t b4 = (size_t)grow * 64 + lane;
        ushort4 g4 = *(const ushort4*)&gs[rowloc][lane * 4];
        float4 x4 = make_float4(0.f, 0.f, 0.f, 0.f);
        if (lane < 32) {
            ushort4 v = ((const ushort4*)xb)[(size_t)grow * 32 + lane];
            x4.x = bf2f(v.x); x4.y = bf2f(v.y); x4.z = bf2f(v.z); x4.w = bf2f(v.w);
        }
        float zv0 = bf2f(z4.x), zv1 = bf2f(z4.y), zv2 = bf2f(z4.z), zv3 = bf2f(z4.w);
        float f0 = al * (azv.x - zv0) + bf2f(g4.x) + x4.x;
        float f1 = al * (azv.y - zv1) + bf2f(g4.y) + x4.y;
        float f2 = al * (azv.z - zv2) + bf2f(g4.z) + x4.z;
        float f3 = al * (azv.w - zv3) + bf2f(g4.w) + x4.w;
        if (mode == 0) {
            ushort4 o;
            o.x = (uint16_t)f2bf(zv0 + c1 * f0); o.y = (uint16_t)f2bf(zv1 + c1 * f1);
            o.z = (uint16_t)f2bf(zv2 + c1 * f2); o.w = (uint16_t)f2bf(zv3 + c1 * f3);
            ((ushort4*)zout)[b4] = o;
        } else if (mode == 1) {
            ushort4 zb = ((const ushort4*)znb)[b4];
            float zb0 = bf2f(zb.x), zb1 = bf2f(zb.y), zb2 = bf2f(zb.z), zb3 = bf2f(zb.w);
            float z20 = zb0 + c1 * f0, z21 = zb1 + c1 * f1;
            float z22 = zb2 + c1 * f2, z23 = zb3 + c1 * f3;
            ushort4 o, p;
            o.x = (uint16_t)f2bf(z20); o.y = (uint16_t)f2bf(z21);
            o.z = (uint16_t)f2bf(z22); o.w = (uint16_t)f2bf(z23);
            p.x = (uint16_t)f2bf(zv0 + 2.f * z20 - 3.f * zb0);
            p.y = (uint16_t)f2bf(zv1 + 2.f * z21 - 3.f * zb1);
            p.z = (uint16_t)f2bf(zv2 + 2.f * z22 - 3.f * zb2);
            p.w = (uint16_t)f2bf(zv3 + 2.f * z23 - 3.f * zb3);
            ((ushort4*)zout)[b4] = o;
            ((ushort4*)Pout)[b4] = p;
        } else if (mode == 2) {
            ushort4 zb = ((const ushort4*)znb)[b4];
            ushort4 o;
            o.x = (uint16_t)f2bf(bf2f(zb.x) + c1 * f0);
            o.y = (uint16_t)f2bf(bf2f(zb.y) + c1 * f1);
            o.z = (uint16_t)f2bf(bf2f(zb.z) + c1 * f2);
            o.w = (uint16_t)f2bf(bf2f(zb.w) + c1 * f3);
            ((ushort4*)zout)[b4] = o;
        } else {
            // znew = znb + (P + z3 - znb)/3 + c2*f
            ushort4 zb = ((const ushort4*)znb)[b4];
            ushort4 p4 = ((const ushort4*)Pin)[b4];
            const float third = 1.f / 3.f;
            float zb0 = bf2f(zb.x), zb1 = bf2f(zb.y), zb2 = bf2f(zb.z), zb3 = bf2f(zb.w);
            float r0v = zb0 + (bf2f(p4.x) + zv0 - zb0) * third + c2 * f0;
            float r1v = zb1 + (bf2f(p4.y) + zv1 - zb1) * third + c2 * f1;
            float r2v = zb2 + (bf2f(p4.z) + zv2 - zb2) * third + c2 * f2;
            float r3v = zb3 + (bf2f(p4.w) + zv3 - zb3) * third + c2 * f3;
            if (mode == 3) {
                ushort4 o;
                o.x = (uint16_t)f2bf(r0v); o.y = (uint16_t)f2bf(r1v);
                o.z = (uint16_t)f2bf(r2v); o.w = (uint16_t)f2bf(r3v);
                ((ushort4*)zout)[b4] = o;
            } else {
                if (lane < 32) {
                    float4 o;
                    o.x = r0v; o.y = r1v; o.z = r2v; o.w = r3v;
                    ((float4*)out)[(size_t)grow * 32 + lane] = o;
                }
            }
        }
    }
}

__global__ void k_fill(float* __restrict__ out, int n, float v) {
    int idx = blockIdx.x * blockDim.x + threadIdx.x;
    if (idx < n) out[idx] = v;
}

static inline size_t alignup(size_t v) { return (v + 255) & ~(size_t)255; }

extern "C" void kernel_launch(void* const* d_in, const int* in_sizes, int n_in,
                              void* d_out, int out_size, void* d_ws, size_t ws_size,
                              hipStream_t stream) {
    const float* x      = (const float*)d_in[0];
    const int*   erow   = (const int*)d_in[1];
    const int*   ecol   = (const int*)d_in[2];
    const float* evals  = (const float*)d_in[3];
    const float* W_ih   = (const float*)d_in[4];
    const float* W_hh   = (const float*)d_in[5];
    const float* b_ih   = (const float*)d_in[6];
    const float* b_hh   = (const float*)d_in[7];
    const float* h      = (const float*)d_in[8];
    const float* alpha0 = (const float*)d_in[9];
    const float* W      = (const float*)d_in[10];
    const float* dvec   = (const float*)d_in[11];

    int N = in_sizes[0] / DINF;
    int E = in_sizes[1];

    char* w = (char*)d_ws;
    uint16_t* znb = (uint16_t*)w; w += alignup((size_t)N * DD * 2);   //  51.2 MB
    uint16_t* B1  = (uint16_t*)w; w += alignup((size_t)N * DD * 2);   //  51.2 MB (z1 / z3)
    uint16_t* P   = (uint16_t*)w; w += alignup((size_t)N * DD * 2);   //  51.2 MB (D-fold)
    uint16_t* xb  = (uint16_t*)w; w += alignup((size_t)N * DINF * 2); //  25.6 MB
    float* alpha = (float*)w;     w += alignup((size_t)N * 4);
    uint16_t* Mpk = (uint16_t*)w; w += alignup((size_t)DD * DD * 2);
    int* counts = (int*)w;        w += alignup((size_t)(N + 1) * 4);  // reused as cursor
    int* row_ptr = (int*)w;       w += alignup((size_t)(N + 1) * 4);
    int* blksum = (int*)w;        w += alignup((size_t)1024 * 4);
    int* cols_s = (int*)w;        w += alignup((size_t)E * 4);
    float* vals_s = (float*)w;    w += alignup((size_t)E * 4);
    int* perm = (int*)w;          w += alignup((size_t)N * 4);        // degree-sorted rows
    int* dbins = (int*)w;         w += alignup((size_t)64 * 4);
    size_t need = (size_t)(w - (char*)d_ws);   // ~188 MB

    // B2 (z2) lives in d_out (N*128 f32 = N*256 bf16 exactly); dead after eval3's
    // gather; final mode-4 eval overwrites d_out with the fp32 result.
    uint16_t* B2 = (uint16_t*)d_out;

    if (ws_size < need) {
        k_fill<<<(out_size + 255) / 256, 256, 0, stream>>>((float*)d_out, out_size, 1000.0f);
        return;
    }

    int n1 = N + 1, nb = (n1 + 1023) / 1024;
    hipMemsetAsync(counts, 0, (size_t)n1 * 4, stream);
    k_hist<<<(E + 255) / 256, 256, 0, stream>>>(erow, counts, E);
    k_scan1<<<nb, 1024, 0, stream>>>(counts, row_ptr, blksum, n1);
    k_scan2<<<1, 1024, 0, stream>>>(blksum, nb);
    k_scan3<<<(n1 + 255) / 256, 256, 0, stream>>>(blksum, row_ptr, counts, n1);
    k_scatter<<<(E + 255) / 256, 256, 0, stream>>>(erow, ecol, evals, counts, cols_s, vals_s, E);

    // degree counting-sort -> perm (equal-degree blocks for k_fused)
    hipMemsetAsync(dbins, 0, 64 * 4, stream);
    k_dhist<<<(N + 255) / 256, 256, 0, stream>>>(row_ptr, dbins, N);
    k_dscan<<<1, 64, 0, stream>>>(dbins);
    k_dscatter<<<(N + 255) / 256, 256, 0, stream>>>(row_ptr, dbins, perm, N);

    k_build_m<<<DD, DD, 0, stream>>>(W, dvec, Mpk);
    k_init<<<(N * 64 + 255) / 256, 256, 0, stream>>>(x, alpha0, znb, xb, alpha, N);

    const float dt = 0.45f;  // T_END / N_STEPS
    int ge = (N + 15) / 16;
    for (int s = 0; s < 2; s++) {
        // eval1: znb -> z1 (B1)
        k_fused<<<ge, 512, 0, stream>>>(znb, znb, B1, nullptr, nullptr, nullptr,
                                        Mpk, xb, perm, row_ptr, cols_s, vals_s,
                                        W_ih, W_hh, b_ih, b_hh, h, alpha,
                                        N, 0, 0.5f * dt, 0.f);
        // eval2: z1 (B1) -> z2 (B2=d_out), D -> P
        k_fused<<<ge, 512, 0, stream>>>(B1, znb, B2, P, nullptr, nullptr,
                                        Mpk, xb, perm, row_ptr, cols_s, vals_s,
                                        W_ih, W_hh, b_ih, b_hh, h, alpha,
                                        N, 1, 0.5f * dt, 0.f);
        // eval3: z2 (B2) -> z3 (B1)
        k_fused<<<ge, 512, 0, stream>>>(B2, znb, B1, nullptr, nullptr, nullptr,
                                        Mpk, xb, perm, row_ptr, cols_s, vals_s,
                                        W_ih, W_hh, b_ih, b_hh, h, alpha,
                                        N, 2, dt, 0.f);
        // eval4: z3 (B1) -> znew
        if (s == 0) {
            k_fused<<<ge, 512, 0, stream>>>(B1, znb, znb, nullptr, P, nullptr,
                                            Mpk, xb, perm, row_ptr, cols_s, vals_s,
                                            W_ih, W_hh, b_ih, b_hh, h, alpha,
                                            N, 3, 0.f, dt / 6.f);
        } else {
            // final: emit fp32 output directly (first 128 cols)
            k_fused<<<ge, 512, 0, stream>>>(B1, znb, nullptr, nullptr, P,
                                            (float*)d_out,
                                            Mpk, xb, perm, row_ptr, cols_s, vals_s,
                                            W_ih, W_hh, b_ih, b_hh, h, alpha,
                                            N, 4, 0.f, dt / 6.f);
        }
    }
}

// Round 13
// 1051.897 us; speedup vs baseline: 2.0037x; 1.3541x over previous
//
#include <hip/hip_runtime.h>
#include <stdint.h>

#define DD 256
#define DINF 128

typedef __attribute__((ext_vector_type(8))) short short8;
typedef __attribute__((ext_vector_type(4))) float f32x4;

__device__ __forceinline__ short f2bf(float f) {
    union { float f; uint32_t u; } c{f};
    uint32_t r = (c.u + 0x7fffu + ((c.u >> 16) & 1u)) >> 16;
    return (short)(uint16_t)r;
}

__device__ __forceinline__ float bf2f(uint16_t b) {
    union { uint32_t u; float f; } c;
    c.u = ((uint32_t)b) << 16;
    return c.f;
}

// ---------------- CSR build ----------------
__global__ void k_hist(const int* __restrict__ rows, int* __restrict__ counts, int E) {
    int e = blockIdx.x * blockDim.x + threadIdx.x;
    if (e < E) atomicAdd(&counts[rows[e] + 1], 1);
}

__global__ void k_scan1(const int* __restrict__ counts, int* __restrict__ part,
                        int* __restrict__ blksum, int n1) {
    __shared__ int tmp[1024];
    int b = blockIdx.x, t = threadIdx.x, i = b * 1024 + t;
    int v = (i < n1) ? counts[i] : 0;
    tmp[t] = v;
    __syncthreads();
    for (int off = 1; off < 1024; off <<= 1) {
        int a = (t >= off) ? tmp[t - off] : 0;
        __syncthreads();
        tmp[t] += a;
        __syncthreads();
    }
    if (i < n1) part[i] = tmp[t];
    if (t == 1023) blksum[b] = tmp[t];
}

__global__ void k_scan2(int* __restrict__ blksum, int nb) {
    __shared__ int tmp[1024];
    int t = threadIdx.x;
    int v = (t < nb) ? blksum[t] : 0;
    tmp[t] = v;
    __syncthreads();
    for (int off = 1; off < 1024; off <<= 1) {
        int a = (t >= off) ? tmp[t - off] : 0;
        __syncthreads();
        tmp[t] += a;
        __syncthreads();
    }
    if (t < nb) blksum[t] = tmp[t];
}

__global__ void k_scan3(const int* __restrict__ blksum, int* __restrict__ row_ptr,
                        int* __restrict__ cursor, int n1) {
    int i = blockIdx.x * blockDim.x + threadIdx.x;
    if (i < n1) {
        int b = i >> 10;
        int off = (b > 0) ? blksum[b - 1] : 0;
        int v = row_ptr[i] + off;
        row_ptr[i] = v;
        cursor[i] = v;
    }
}

__global__ void k_scatter(const int* __restrict__ rows, const int* __restrict__ cols,
                          const float* __restrict__ vals, int* __restrict__ cursor,
                          int* __restrict__ cols_s, float* __restrict__ vals_s, int E) {
    int e = blockIdx.x * blockDim.x + threadIdx.x;
    if (e < E) {
        int r = rows[e];
        int pos = atomicAdd(&cursor[r], 1);
        cols_s[pos] = cols[e];
        vals_s[pos] = vals[e];
    }
}

// ---------------- degree counting-sort (two-level atomics: LDS then global) -------
__global__ void k_dhist(const int* __restrict__ row_ptr, int* __restrict__ dbins, int N) {
    __shared__ int lbin[64];
    int t = threadIdx.x;
    if (t < 64) lbin[t] = 0;
    __syncthreads();
    int i = blockIdx.x * blockDim.x + t;
    if (i < N) {
        int d = row_ptr[i + 1] - row_ptr[i];
        if (d > 63) d = 63;
        atomicAdd(&lbin[d], 1);          // LDS atomic: intra-block only
    }
    __syncthreads();
    if (t < 64 && lbin[t] > 0) atomicAdd(&dbins[t], lbin[t]);  // 64 global adds/block
}

__global__ void k_dscan(int* __restrict__ dbins) {   // 1 block, 64 threads
    __shared__ int tmp[64];
    int t = threadIdx.x;
    tmp[t] = dbins[t];
    __syncthreads();
    if (t == 0) {
        int acc = 0;
        for (int i = 0; i < 64; i++) { int v = tmp[i]; tmp[i] = acc; acc += v; }
    }
    __syncthreads();
    dbins[t] = tmp[t];   // exclusive scan -> scatter cursors
}

__global__ void k_dscatter(const int* __restrict__ row_ptr, int* __restrict__ dcursor,
                           int* __restrict__ perm, int N) {
    __shared__ int lbin[64];
    __shared__ int lbase[64];
    int t = threadIdx.x;
    if (t < 64) lbin[t] = 0;
    __syncthreads();
    int i = blockIdx.x * blockDim.x + t;
    bool ok = i < N;
    int d = 0, lpos = 0;
    if (ok) {
        d = row_ptr[i + 1] - row_ptr[i];
        if (d > 63) d = 63;
        lpos = atomicAdd(&lbin[d], 1);   // LDS atomic: local position
    }
    __syncthreads();
    if (t < 64) lbase[t] = (lbin[t] > 0) ? atomicAdd(&dcursor[t], lbin[t]) : 0;
    __syncthreads();
    if (ok) perm[lbase[d] + lpos] = i;
}

// ---------------- M = (W*clip(d))@W^T - I, packed in MFMA B-fragment order --------
// Also sets *mnz = 1 if ANY element of M is nonzero (race-benign store).
// For the common W=I, d=1 input, M == 0 exactly -> k_fused takes the zero-M
// fast path (skips MFMA + barrier entirely).
__global__ void k_build_m(const float* __restrict__ W, const float* __restrict__ dvec,
                          uint16_t* __restrict__ Mpk, int* __restrict__ mnz) {
    __shared__ float u[DD];
    int n = blockIdx.x, k = threadIdx.x;
    float dj = dvec[k];
    dj = fminf(fmaxf(dj, 0.f), 1.f);
    u[k] = W[n * DD + k] * dj;
    __syncthreads();
    float acc = 0.f;
    for (int j = 0; j < DD; j++) acc += u[j] * W[k * DD + j];
    acc -= (n == k) ? 1.f : 0.f;
    if (acc != 0.f) *mnz = 1;
    int tile = n >> 4, m = n & 15, kt = k >> 5, quad = (k >> 3) & 3, j = k & 7;
    int lane = quad * 16 + m;
    Mpk[(((tile * 8 + kt) * 64 + lane) << 3) + j] = (uint16_t)f2bf(acc);
}

// ---------------- init: znb = bf16([x,0]), xb = bf16(x), alpha = alpha0 ----------------
__global__ void k_init(const float* __restrict__ x, const float* __restrict__ alpha0,
                       uint16_t* __restrict__ znb, uint16_t* __restrict__ xb,
                       float* __restrict__ alpha, int N) {
    int idx = blockIdx.x * blockDim.x + threadIdx.x;
    int total = N * 64;
    if (idx < total) {
        int row = idx >> 6, c4 = idx & 63;
        float4 v = make_float4(0.f, 0.f, 0.f, 0.f);
        if (c4 < 32) v = ((const float4*)x)[(size_t)row * 32 + c4];
        ushort4 b;
        b.x = (uint16_t)f2bf(v.x); b.y = (uint16_t)f2bf(v.y);
        b.z = (uint16_t)f2bf(v.z); b.w = (uint16_t)f2bf(v.w);
        ((ushort4*)znb)[idx] = b;
        if (c4 < 32) ((ushort4*)xb)[(size_t)row * 32 + c4] = b;
    }
    if (idx < N) alpha[idx] = alpha0[idx];
}

// ---------------- fused eval (gather + alpha + optional z@M + RK4) ----------------
// Block = 512 threads (8 waves), 16 rows = perm[16b..16b+15]. Wave w
// gathers/combines rows perm[16b+2w], perm[16b+2w+1]. If *mnz == 0 (M == 0),
// the MFMA + barrier + gs path is skipped entirely: waves run fully
// independently (no block-level synchronization at all).
// f = alph*(az - z) + z@M + x0
// mode 0: zout = bf16(z + c1*f)
// mode 1: z2f = znb + c1*f; zout = bf16(z2f); Pout = bf16(z + 2*z2f - 3*znb)
// mode 2: zout = bf16(znb + c1*f)
// mode 3: znew = znb + (P + z - znb)/3 + c2*f; zout = bf16(znew)
// mode 4: same as 3 but f32 out (first 128 cols), no zout
__global__ __launch_bounds__(512, 6) void k_fused(
    const uint16_t* zsrc, const uint16_t* znb, uint16_t* zout,
    uint16_t* __restrict__ Pout, const uint16_t* __restrict__ Pin,
    float* __restrict__ out,
    const uint16_t* __restrict__ Mpk, const uint16_t* __restrict__ xb,
    const int* __restrict__ perm, const int* __restrict__ mnz,
    const int* __restrict__ row_ptr, const int* __restrict__ cols_s,
    const float* __restrict__ vals_s,
    const float* __restrict__ W_ih, const float* __restrict__ W_hh,
    const float* __restrict__ b_ih, const float* __restrict__ b_hh,
    const float* __restrict__ hbuf, float* __restrict__ alpha,
    int N, int mode, float c1, float c2)
{
    __shared__ uint16_t gs[16][264];   // z@M result, bf16  ~8.4 KB (unused if M==0)

    int t = threadIdx.x;
    int wv = t >> 6;            // 0..7
    int lane = t & 63;
    int r0 = blockIdx.x * 16;

    bool usem = (*mnz != 0);    // block-uniform

    int row0 = wv * 2, row1 = wv * 2 + 1;
    int i0 = r0 + row0, i1 = r0 + row1;
    bool ok0 = i0 < N, ok1 = i1 < N;
    int g0 = ok0 ? perm[i0] : 0;
    int g1 = ok1 ? perm[i1] : 0;

    // own-row eval points (cols 4*lane..+3)
    ushort4 zr0 = ok0 ? ((const ushort4*)zsrc)[(size_t)g0 * 64 + lane] : make_ushort4(0,0,0,0);
    ushort4 zr1 = ok1 ? ((const ushort4*)zsrc)[(size_t)g1 * 64 + lane] : make_ushort4(0,0,0,0);

    // ---- gather both rows (az in f32 regs), interleaved chunk-4 ----
    int s0e = ok0 ? row_ptr[g0] : 0, e0e = ok0 ? row_ptr[g0 + 1] : 0;
    int s1e = ok1 ? row_ptr[g1] : 0, e1e = ok1 ? row_ptr[g1 + 1] : 0;
    int d0 = e0e - s0e, d1 = e1e - s1e;
    int dmax = (d0 > d1) ? d0 : d1;
    float4 az0 = make_float4(0.f, 0.f, 0.f, 0.f);
    float4 az1 = make_float4(0.f, 0.f, 0.f, 0.f);
    for (int i = 0; i < dmax; i += 4) {
        if (i < d0) {
            int rem = d0 - i, base = s0e + i;
            int ca = cols_s[base];
            float va = vals_s[base];
            int cb = 0, cc = 0, cd = 0;
            float vb = 0.f, vc = 0.f, vd = 0.f;
            if (rem > 1) { cb = cols_s[base + 1]; vb = vals_s[base + 1]; }
            if (rem > 2) { cc = cols_s[base + 2]; vc = vals_s[base + 2]; }
            if (rem > 3) { cd = cols_s[base + 3]; vd = vals_s[base + 3]; }
            ushort4 ra = ((const ushort4*)zsrc)[(size_t)ca * 64 + lane];
            ushort4 rb = (rem > 1) ? ((const ushort4*)zsrc)[(size_t)cb * 64 + lane] : make_ushort4(0,0,0,0);
            ushort4 rc = (rem > 2) ? ((const ushort4*)zsrc)[(size_t)cc * 64 + lane] : make_ushort4(0,0,0,0);
            ushort4 rd = (rem > 3) ? ((const ushort4*)zsrc)[(size_t)cd * 64 + lane] : make_ushort4(0,0,0,0);
            az0.x += va * bf2f(ra.x) + vb * bf2f(rb.x) + vc * bf2f(rc.x) + vd * bf2f(rd.x);
            az0.y += va * bf2f(ra.y) + vb * bf2f(rb.y) + vc * bf2f(rc.y) + vd * bf2f(rd.y);
            az0.z += va * bf2f(ra.z) + vb * bf2f(rb.z) + vc * bf2f(rc.z) + vd * bf2f(rd.z);
            az0.w += va * bf2f(ra.w) + vb * bf2f(rb.w) + vc * bf2f(rc.w) + vd * bf2f(rd.w);
        }
        if (i < d1) {
            int rem = d1 - i, base = s1e + i;
            int ca = cols_s[base];
            float va = vals_s[base];
            int cb = 0, cc = 0, cd = 0;
            float vb = 0.f, vc = 0.f, vd = 0.f;
            if (rem > 1) { cb = cols_s[base + 1]; vb = vals_s[base + 1]; }
            if (rem > 2) { cc = cols_s[base + 2]; vc = vals_s[base + 2]; }
            if (rem > 3) { cd = cols_s[base + 3]; vd = vals_s[base + 3]; }
            ushort4 ra = ((const ushort4*)zsrc)[(size_t)ca * 64 + lane];
            ushort4 rb = (rem > 1) ? ((const ushort4*)zsrc)[(size_t)cb * 64 + lane] : make_ushort4(0,0,0,0);
            ushort4 rc = (rem > 2) ? ((const ushort4*)zsrc)[(size_t)cc * 64 + lane] : make_ushort4(0,0,0,0);
            ushort4 rd = (rem > 3) ? ((const ushort4*)zsrc)[(size_t)cd * 64 + lane] : make_ushort4(0,0,0,0);
            az1.x += va * bf2f(ra.x) + vb * bf2f(rb.x) + vc * bf2f(rc.x) + vd * bf2f(rd.x);
            az1.y += va * bf2f(ra.y) + vb * bf2f(rb.y) + vc * bf2f(rc.y) + vd * bf2f(rd.y);
            az1.z += va * bf2f(ra.z) + vb * bf2f(rb.z) + vc * bf2f(rc.z) + vd * bf2f(rd.z);
            az1.w += va * bf2f(ra.w) + vb * bf2f(rb.w) + vc * bf2f(rc.w) + vd * bf2f(rd.w);
        }
    }

    // ---- z@M via MFMA: only when M != 0 (block-uniform branch) ----
    if (usem) {
        int m = lane & 15, quad = lane >> 4;
        int t0 = wv * 2, t1 = wv * 2 + 1;
        int ia = r0 + m;
        bool aok = ia < N;
        int arow_g = aok ? perm[ia] : 0;
        f32x4 acc0 = {0.f, 0.f, 0.f, 0.f};
        f32x4 acc1 = {0.f, 0.f, 0.f, 0.f};
        #pragma unroll
        for (int kt = 0; kt < 8; kt++) {
            short8 a = aok ? *(const short8*)(zsrc + (size_t)arow_g * 256 + kt * 32 + quad * 8)
                           : short8{0, 0, 0, 0, 0, 0, 0, 0};
            short8 b0 = ((const short8*)Mpk)[(t0 * 8 + kt) * 64 + lane];
            short8 b1 = ((const short8*)Mpk)[(t1 * 8 + kt) * 64 + lane];
            acc0 = __builtin_amdgcn_mfma_f32_16x16x32_bf16(a, b0, acc0, 0, 0, 0);
            acc1 = __builtin_amdgcn_mfma_f32_16x16x32_bf16(a, b1, acc1, 0, 0, 0);
        }
        // C layout: col = lane&15, row = quad*4 + r
        #pragma unroll
        for (int r = 0; r < 4; r++) {
            gs[quad * 4 + r][t0 * 16 + m] = (uint16_t)f2bf(acc0[r]);
            gs[quad * 4 + r][t1 * 16 + m] = (uint16_t)f2bf(acc1[r]);
        }
    }

    // ---- alpha RNN update for both rows ----
    float4 wih0 = ((const float4*)W_ih)[lane];
    float4 wih1 = ((const float4*)(W_ih + DD))[lane];
    float z00 = bf2f(zr0.x), z01 = bf2f(zr0.y), z02 = bf2f(zr0.z), z03 = bf2f(zr0.w);
    float z10 = bf2f(zr1.x), z11 = bf2f(zr1.y), z12 = bf2f(zr1.z), z13 = bf2f(zr1.w);
    float s00 = z00 * wih0.x + z01 * wih0.y + z02 * wih0.z + z03 * wih0.w;
    float s01 = z00 * wih1.x + z01 * wih1.y + z02 * wih1.z + z03 * wih1.w;
    float s10 = z10 * wih0.x + z11 * wih0.y + z12 * wih0.z + z13 * wih0.w;
    float s11 = z10 * wih1.x + z11 * wih1.y + z12 * wih1.z + z13 * wih1.w;
    #pragma unroll
    for (int off = 32; off >= 1; off >>= 1) {
        s00 += __shfl_down(s00, off, 64);
        s01 += __shfl_down(s01, off, 64);
        s10 += __shfl_down(s10, off, 64);
        s11 += __shfl_down(s11, off, 64);
    }
    float alph0 = 0.f, alph1 = 0.f;
    if (lane == 0) {
        float bi0 = b_ih[0] + b_hh[0], bi1 = b_ih[1] + b_hh[1];
        float wh0 = W_hh[0], wh1 = W_hh[1], wh2 = W_hh[2], wh3 = W_hh[3];
        if (ok0) {
            float h0 = hbuf[g0 * 2], h1 = hbuf[g0 * 2 + 1];
            float anew = alpha[g0] * tanhf(s00 + bi0 + h0 * wh0 + h1 * wh1)
                       + tanhf(s01 + bi1 + h0 * wh2 + h1 * wh3);
            alpha[g0] = anew;
            alph0 = 0.5f / (1.f + expf(-anew));
        }
        if (ok1) {
            float h0 = hbuf[g1 * 2], h1 = hbuf[g1 * 2 + 1];
            float anew = alpha[g1] * tanhf(s10 + bi0 + h0 * wh0 + h1 * wh1)
                       + tanhf(s11 + bi1 + h0 * wh2 + h1 * wh3);
            alpha[g1] = anew;
            alph1 = 0.5f / (1.f + expf(-anew));
        }
    }
    alph0 = __shfl(alph0, 0, 64);
    alph1 = __shfl(alph1, 0, 64);

    if (usem) __syncthreads();   // only needed to publish gs

    // ---- combine + RK4 for this wave's two rows ----
    #pragma unroll
    for (int rr = 0; rr < 2; rr++) {
        int rowloc = (rr == 0) ? row0 : row1;
        int grow = (rr == 0) ? g0 : g1;
        bool ok = (rr == 0) ? ok0 : ok1;
        if (!ok) continue;
        float4 azv = (rr == 0) ? az0 : az1;
        ushort4 z4 = (rr == 0) ? zr0 : zr1;
        float al = (rr == 0) ? alph0 : alph1;
        size_t b4 = (size_t)grow * 64 + lane;
        float gv0 = 0.f, gv1 = 0.f, gv2 = 0.f, gv3 = 0.f;
        if (usem) {
            ushort4 g4 = *(const ushort4*)&gs[rowloc][lane * 4];
            gv0 = bf2f(g4.x); gv1 = bf2f(g4.y); gv2 = bf2f(g4.z); gv3 = bf2f(g4.w);
        }
        float4 x4 = make_float4(0.f, 0.f, 0.f, 0.f);
        if (lane < 32) {
            ushort4 v = ((const ushort4*)xb)[(size_t)grow * 32 + lane];
            x4.x = bf2f(v.x); x4.y = bf2f(v.y); x4.z = bf2f(v.z); x4.w = bf2f(v.w);
        }
        float zv0 = bf2f(z4.x), zv1 = bf2f(z4.y), zv2 = bf2f(z4.z), zv3 = bf2f(z4.w);
        float f0 = al * (azv.x - zv0) + gv0 + x4.x;
        float f1 = al * (azv.y - zv1) + gv1 + x4.y;
        float f2 = al * (azv.z - zv2) + gv2 + x4.z;
        float f3 = al * (azv.w - zv3) + gv3 + x4.w;
        if (mode == 0) {
            ushort4 o;
            o.x = (uint16_t)f2bf(zv0 + c1 * f0); o.y = (uint16_t)f2bf(zv1 + c1 * f1);
            o.z = (uint16_t)f2bf(zv2 + c1 * f2); o.w = (uint16_t)f2bf(zv3 + c1 * f3);
            ((ushort4*)zout)[b4] = o;
        } else if (mode == 1) {
            ushort4 zb = ((const ushort4*)znb)[b4];
            float zb0 = bf2f(zb.x), zb1 = bf2f(zb.y), zb2 = bf2f(zb.z), zb3 = bf2f(zb.w);
            float z20 = zb0 + c1 * f0, z21 = zb1 + c1 * f1;
            float z22 = zb2 + c1 * f2, z23 = zb3 + c1 * f3;
            ushort4 o, p;
            o.x = (uint16_t)f2bf(z20); o.y = (uint16_t)f2bf(z21);
            o.z = (uint16_t)f2bf(z22); o.w = (uint16_t)f2bf(z23);
            p.x = (uint16_t)f2bf(zv0 + 2.f * z20 - 3.f * zb0);
            p.y = (uint16_t)f2bf(zv1 + 2.f * z21 - 3.f * zb1);
            p.z = (uint16_t)f2bf(zv2 + 2.f * z22 - 3.f * zb2);
            p.w = (uint16_t)f2bf(zv3 + 2.f * z23 - 3.f * zb3);
            ((ushort4*)zout)[b4] = o;
            ((ushort4*)Pout)[b4] = p;
        } else if (mode == 2) {
            ushort4 zb = ((const ushort4*)znb)[b4];
            ushort4 o;
            o.x = (uint16_t)f2bf(bf2f(zb.x) + c1 * f0);
            o.y = (uint16_t)f2bf(bf2f(zb.y) + c1 * f1);
            o.z = (uint16_t)f2bf(bf2f(zb.z) + c1 * f2);
            o.w = (uint16_t)f2bf(bf2f(zb.w) + c1 * f3);
            ((ushort4*)zout)[b4] = o;
        } else {
            // znew = znb + (P + z3 - znb)/3 + c2*f
            ushort4 zb = ((const ushort4*)znb)[b4];
            ushort4 p4 = ((const ushort4*)Pin)[b4];
            const float third = 1.f / 3.f;
            float zb0 = bf2f(zb.x), zb1 = bf2f(zb.y), zb2 = bf2f(zb.z), zb3 = bf2f(zb.w);
            float r0v = zb0 + (bf2f(p4.x) + zv0 - zb0) * third + c2 * f0;
            float r1v = zb1 + (bf2f(p4.y) + zv1 - zb1) * third + c2 * f1;
            float r2v = zb2 + (bf2f(p4.z) + zv2 - zb2) * third + c2 * f2;
            float r3v = zb3 + (bf2f(p4.w) + zv3 - zb3) * third + c2 * f3;
            if (mode == 3) {
                ushort4 o;
                o.x = (uint16_t)f2bf(r0v); o.y = (uint16_t)f2bf(r1v);
                o.z = (uint16_t)f2bf(r2v); o.w = (uint16_t)f2bf(r3v);
                ((ushort4*)zout)[b4] = o;
            } else {
                if (lane < 32) {
                    float4 o;
                    o.x = r0v; o.y = r1v; o.z = r2v; o.w = r3v;
                    ((float4*)out)[(size_t)grow * 32 + lane] = o;
                }
            }
        }
    }
}

__global__ void k_fill(float* __restrict__ out, int n, float v) {
    int idx = blockIdx.x * blockDim.x + threadIdx.x;
    if (idx < n) out[idx] = v;
}

static inline size_t alignup(size_t v) { return (v + 255) & ~(size_t)255; }

extern "C" void kernel_launch(void* const* d_in, const int* in_sizes, int n_in,
                              void* d_out, int out_size, void* d_ws, size_t ws_size,
                              hipStream_t stream) {
    const float* x      = (const float*)d_in[0];
    const int*   erow   = (const int*)d_in[1];
    const int*   ecol   = (const int*)d_in[2];
    const float* evals  = (const float*)d_in[3];
    const float* W_ih   = (const float*)d_in[4];
    const float* W_hh   = (const float*)d_in[5];
    const float* b_ih   = (const float*)d_in[6];
    const float* b_hh   = (const float*)d_in[7];
    const float* h      = (const float*)d_in[8];
    const float* alpha0 = (const float*)d_in[9];
    const float* W      = (const float*)d_in[10];
    const float* dvec   = (const float*)d_in[11];

    int N = in_sizes[0] / DINF;
    int E = in_sizes[1];

    char* w = (char*)d_ws;
    uint16_t* znb = (uint16_t*)w; w += alignup((size_t)N * DD * 2);   //  51.2 MB
    uint16_t* B1  = (uint16_t*)w; w += alignup((size_t)N * DD * 2);   //  51.2 MB (z1 / z3)
    uint16_t* P   = (uint16_t*)w; w += alignup((size_t)N * DD * 2);   //  51.2 MB (D-fold)
    uint16_t* xb  = (uint16_t*)w; w += alignup((size_t)N * DINF * 2); //  25.6 MB
    float* alpha = (float*)w;     w += alignup((size_t)N * 4);
    uint16_t* Mpk = (uint16_t*)w; w += alignup((size_t)DD * DD * 2);
    int* counts = (int*)w;        w += alignup((size_t)(N + 1) * 4);  // reused as cursor
    int* row_ptr = (int*)w;       w += alignup((size_t)(N + 1) * 4);
    int* blksum = (int*)w;        w += alignup((size_t)1024 * 4);
    int* cols_s = (int*)w;        w += alignup((size_t)E * 4);
    float* vals_s = (float*)w;    w += alignup((size_t)E * 4);
    int* perm = (int*)w;          w += alignup((size_t)N * 4);        // degree-sorted rows
    int* dbins = (int*)w;         w += alignup((size_t)64 * 4);
    int* mnz = (int*)w;           w += alignup((size_t)4);            // M-nonzero flag
    size_t need = (size_t)(w - (char*)d_ws);   // ~188 MB

    // B2 (z2) lives in d_out (N*128 f32 = N*256 bf16 exactly); dead after eval3's
    // gather; final mode-4 eval overwrites d_out with the fp32 result.
    uint16_t* B2 = (uint16_t*)d_out;

    if (ws_size < need) {
        k_fill<<<(out_size + 255) / 256, 256, 0, stream>>>((float*)d_out, out_size, 1000.0f);
        return;
    }

    int n1 = N + 1, nb = (n1 + 1023) / 1024;
    hipMemsetAsync(counts, 0, (size_t)n1 * 4, stream);
    hipMemsetAsync(mnz, 0, 4, stream);
    k_hist<<<(E + 255) / 256, 256, 0, stream>>>(erow, counts, E);
    k_scan1<<<nb, 1024, 0, stream>>>(counts, row_ptr, blksum, n1);
    k_scan2<<<1, 1024, 0, stream>>>(blksum, nb);
    k_scan3<<<(n1 + 255) / 256, 256, 0, stream>>>(blksum, row_ptr, counts, n1);
    k_scatter<<<(E + 255) / 256, 256, 0, stream>>>(erow, ecol, evals, counts, cols_s, vals_s, E);

    // degree counting-sort -> perm (equal-degree blocks for k_fused)
    hipMemsetAsync(dbins, 0, 64 * 4, stream);
    k_dhist<<<(N + 255) / 256, 256, 0, stream>>>(row_ptr, dbins, N);
    k_dscan<<<1, 64, 0, stream>>>(dbins);
    k_dscatter<<<(N + 255) / 256, 256, 0, stream>>>(row_ptr, dbins, perm, N);

    k_build_m<<<DD, DD, 0, stream>>>(W, dvec, Mpk, mnz);
    k_init<<<(N * 64 + 255) / 256, 256, 0, stream>>>(x, alpha0, znb, xb, alpha, N);

    const float dt = 0.45f;  // T_END / N_STEPS
    int ge = (N + 15) / 16;
    for (int s = 0; s < 2; s++) {
        // eval1: znb -> z1 (B1)
        k_fused<<<ge, 512, 0, stream>>>(znb, znb, B1, nullptr, nullptr, nullptr,
                                        Mpk, xb, perm, mnz, row_ptr, cols_s, vals_s,
                                        W_ih, W_hh, b_ih, b_hh, h, alpha,
                                        N, 0, 0.5f * dt, 0.f);
        // eval2: z1 (B1) -> z2 (B2=d_out), D -> P
        k_fused<<<ge, 512, 0, stream>>>(B1, znb, B2, P, nullptr, nullptr,
                                        Mpk, xb, perm, mnz, row_ptr, cols_s, vals_s,
                                        W_ih, W_hh, b_ih, b_hh, h, alpha,
                                        N, 1, 0.5f * dt, 0.f);
        // eval3: z2 (B2) -> z3 (B1)
        k_fused<<<ge, 512, 0, stream>>>(B2, znb, B1, nullptr, nullptr, nullptr,
                                        Mpk, xb, perm, mnz, row_ptr, cols_s, vals_s,
                                        W_ih, W_hh, b_ih, b_hh, h, alpha,
                                        N, 2, dt, 0.f);
        // eval4: z3 (B1) -> znew
        if (s == 0) {
            k_fused<<<ge, 512, 0, stream>>>(B1, znb, znb, nullptr, P, nullptr,
                                            Mpk, xb, perm, mnz, row_ptr, cols_s, vals_s,
                                            W_ih, W_hh, b_ih, b_hh, h, alpha,
                                            N, 3, 0.f, dt / 6.f);
        } else {
            // final: emit fp32 output directly (first 128 cols)
            k_fused<<<ge, 512, 0, stream>>>(B1, znb, nullptr, nullptr, P,
                                            (float*)d_out,
                                            Mpk, xb, perm, mnz, row_ptr, cols_s, vals_s,
                                            W_ih, W_hh, b_ih, b_hh, h, alpha,
                                            N, 4, 0.f, dt / 6.f);
        }
    }
}

// Round 15
// 1024.768 us; speedup vs baseline: 2.0567x; 1.0265x over previous
//
#include <hip/hip_runtime.h>
#include <stdint.h>

#define DD 256
#define DINF 128

typedef __attribute__((ext_vector_type(8))) short short8;
typedef __attribute__((ext_vector_type(4))) float f32x4;

__device__ __forceinline__ short f2bf(float f) {
    union { float f; uint32_t u; } c{f};
    uint32_t r = (c.u + 0x7fffu + ((c.u >> 16) & 1u)) >> 16;
    return (short)(uint16_t)r;
}

__device__ __forceinline__ float bf2f(uint16_t b) {
    union { uint32_t u; float f; } c;
    c.u = ((uint32_t)b) << 16;
    return c.f;
}

// ---------------- CSR build ----------------
__global__ void k_hist(const int* __restrict__ rows, int* __restrict__ counts, int E) {
    int e = blockIdx.x * blockDim.x + threadIdx.x;
    if (e < E) atomicAdd(&counts[rows[e] + 1], 1);
}

__global__ void k_scan1(const int* __restrict__ counts, int* __restrict__ part,
                        int* __restrict__ blksum, int n1) {
    __shared__ int tmp[1024];
    int b = blockIdx.x, t = threadIdx.x, i = b * 1024 + t;
    int v = (i < n1) ? counts[i] : 0;
    tmp[t] = v;
    __syncthreads();
    for (int off = 1; off < 1024; off <<= 1) {
        int a = (t >= off) ? tmp[t - off] : 0;
        __syncthreads();
        tmp[t] += a;
        __syncthreads();
    }
    if (i < n1) part[i] = tmp[t];
    if (t == 1023) blksum[b] = tmp[t];
}

__global__ void k_scan2(int* __restrict__ blksum, int nb) {
    __shared__ int tmp[1024];
    int t = threadIdx.x;
    int v = (t < nb) ? blksum[t] : 0;
    tmp[t] = v;
    __syncthreads();
    for (int off = 1; off < 1024; off <<= 1) {
        int a = (t >= off) ? tmp[t - off] : 0;
        __syncthreads();
        tmp[t] += a;
        __syncthreads();
    }
    if (t < nb) blksum[t] = tmp[t];
}

__global__ void k_scan3(const int* __restrict__ blksum, int* __restrict__ row_ptr,
                        int* __restrict__ cursor, int n1) {
    int i = blockIdx.x * blockDim.x + threadIdx.x;
    if (i < n1) {
        int b = i >> 10;
        int off = (b > 0) ? blksum[b - 1] : 0;
        int v = row_ptr[i] + off;
        row_ptr[i] = v;
        cursor[i] = v;
    }
}

__global__ void k_scatter(const int* __restrict__ rows, const int* __restrict__ cols,
                          const float* __restrict__ vals, int* __restrict__ cursor,
                          int* __restrict__ cols_s, float* __restrict__ vals_s, int E) {
    int e = blockIdx.x * blockDim.x + threadIdx.x;
    if (e < E) {
        int r = rows[e];
        int pos = atomicAdd(&cursor[r], 1);
        cols_s[pos] = cols[e];
        vals_s[pos] = vals[e];
    }
}

// ---------------- M = (W*clip(d))@W^T - I, packed in MFMA B-fragment order --------
// Also sets *mnz = 1 if ANY element of M is nonzero (race-benign store).
// For the common W=I, d=1 input, M == 0 exactly -> k_fused takes the zero-M
// fast path (skips MFMA + barrier entirely).
__global__ void k_build_m(const float* __restrict__ W, const float* __restrict__ dvec,
                          uint16_t* __restrict__ Mpk, int* __restrict__ mnz) {
    __shared__ float u[DD];
    int n = blockIdx.x, k = threadIdx.x;
    float dj = dvec[k];
    dj = fminf(fmaxf(dj, 0.f), 1.f);
    u[k] = W[n * DD + k] * dj;
    __syncthreads();
    float acc = 0.f;
    for (int j = 0; j < DD; j++) acc += u[j] * W[k * DD + j];
    acc -= (n == k) ? 1.f : 0.f;
    if (acc != 0.f) *mnz = 1;
    int tile = n >> 4, m = n & 15, kt = k >> 5, quad = (k >> 3) & 3, j = k & 7;
    int lane = quad * 16 + m;
    Mpk[(((tile * 8 + kt) * 64 + lane) << 3) + j] = (uint16_t)f2bf(acc);
}

// ---------------- init: znb = bf16([x,0]), xb = bf16(x), alpha = alpha0 ----------------
__global__ void k_init(const float* __restrict__ x, const float* __restrict__ alpha0,
                       uint16_t* __restrict__ znb, uint16_t* __restrict__ xb,
                       float* __restrict__ alpha, int N) {
    int idx = blockIdx.x * blockDim.x + threadIdx.x;
    int total = N * 64;
    if (idx < total) {
        int row = idx >> 6, c4 = idx & 63;
        float4 v = make_float4(0.f, 0.f, 0.f, 0.f);
        if (c4 < 32) v = ((const float4*)x)[(size_t)row * 32 + c4];
        ushort4 b;
        b.x = (uint16_t)f2bf(v.x); b.y = (uint16_t)f2bf(v.y);
        b.z = (uint16_t)f2bf(v.z); b.w = (uint16_t)f2bf(v.w);
        ((ushort4*)znb)[idx] = b;
        if (c4 < 32) ((ushort4*)xb)[(size_t)row * 32 + c4] = b;
    }
    if (idx < N) alpha[idx] = alpha0[idx];
}

// ---------------- fused eval (gather + alpha + optional z@M + RK4) ----------------
// Block = 512 threads (8 waves), 16 sequential rows. Wave w gathers/combines
// rows 16b+2w, 16b+2w+1. If *mnz == 0 (M == 0), the MFMA + barrier + gs path is
// skipped entirely: waves run fully independently (no block synchronization).
// f = alph*(az - z) + z@M + x0
// mode 0: zout = bf16(z + c1*f)
// mode 1: z2f = znb + c1*f; zout = bf16(z2f); Pout = bf16(z + 2*z2f - 3*znb)
// mode 2: zout = bf16(znb + c1*f)
// mode 3: znew = znb + (P + z - znb)/3 + c2*f; zout = bf16(znew)
// mode 4: same as 3 but f32 out (first 128 cols), no zout
__global__ __launch_bounds__(512, 8) void k_fused(
    const uint16_t* zsrc, const uint16_t* znb, uint16_t* zout,
    uint16_t* __restrict__ Pout, const uint16_t* __restrict__ Pin,
    float* __restrict__ out,
    const uint16_t* __restrict__ Mpk, const uint16_t* __restrict__ xb,
    const int* __restrict__ mnz,
    const int* __restrict__ row_ptr, const int* __restrict__ cols_s,
    const float* __restrict__ vals_s,
    const float* __restrict__ W_ih, const float* __restrict__ W_hh,
    const float* __restrict__ b_ih, const float* __restrict__ b_hh,
    const float* __restrict__ hbuf, float* __restrict__ alpha,
    int N, int mode, float c1, float c2)
{
    __shared__ uint16_t gs[16][264];   // z@M result, bf16  ~8.4 KB (unused if M==0)

    int t = threadIdx.x;
    int wv = t >> 6;            // 0..7
    int lane = t & 63;
    int r0 = blockIdx.x * 16;

    bool usem = (*mnz != 0);    // block-uniform

    int row0 = wv * 2, row1 = wv * 2 + 1;
    int g0 = r0 + row0, g1 = r0 + row1;
    bool ok0 = g0 < N, ok1 = g1 < N;

    // own-row eval points (cols 4*lane..+3)
    ushort4 zr0 = ok0 ? ((const ushort4*)zsrc)[(size_t)g0 * 64 + lane] : make_ushort4(0,0,0,0);
    ushort4 zr1 = ok1 ? ((const ushort4*)zsrc)[(size_t)g1 * 64 + lane] : make_ushort4(0,0,0,0);

    // ---- gather both rows (az in f32 regs), interleaved chunk-4 ----
    int s0e = ok0 ? row_ptr[g0] : 0, e0e = ok0 ? row_ptr[g0 + 1] : 0;
    int s1e = ok1 ? row_ptr[g1] : 0, e1e = ok1 ? row_ptr[g1 + 1] : 0;
    int d0 = e0e - s0e, d1 = e1e - s1e;
    int dmax = (d0 > d1) ? d0 : d1;
    float4 az0 = make_float4(0.f, 0.f, 0.f, 0.f);
    float4 az1 = make_float4(0.f, 0.f, 0.f, 0.f);
    for (int i = 0; i < dmax; i += 4) {
        if (i < d0) {
            int rem = d0 - i, base = s0e + i;
            int ca = cols_s[base];
            float va = vals_s[base];
            int cb = 0, cc = 0, cd = 0;
            float vb = 0.f, vc = 0.f, vd = 0.f;
            if (rem > 1) { cb = cols_s[base + 1]; vb = vals_s[base + 1]; }
            if (rem > 2) { cc = cols_s[base + 2]; vc = vals_s[base + 2]; }
            if (rem > 3) { cd = cols_s[base + 3]; vd = vals_s[base + 3]; }
            ushort4 ra = ((const ushort4*)zsrc)[(size_t)ca * 64 + lane];
            ushort4 rb = (rem > 1) ? ((const ushort4*)zsrc)[(size_t)cb * 64 + lane] : make_ushort4(0,0,0,0);
            ushort4 rc = (rem > 2) ? ((const ushort4*)zsrc)[(size_t)cc * 64 + lane] : make_ushort4(0,0,0,0);
            ushort4 rd = (rem > 3) ? ((const ushort4*)zsrc)[(size_t)cd * 64 + lane] : make_ushort4(0,0,0,0);
            az0.x += va * bf2f(ra.x) + vb * bf2f(rb.x) + vc * bf2f(rc.x) + vd * bf2f(rd.x);
            az0.y += va * bf2f(ra.y) + vb * bf2f(rb.y) + vc * bf2f(rc.y) + vd * bf2f(rd.y);
            az0.z += va * bf2f(ra.z) + vb * bf2f(rb.z) + vc * bf2f(rc.z) + vd * bf2f(rd.z);
            az0.w += va * bf2f(ra.w) + vb * bf2f(rb.w) + vc * bf2f(rc.w) + vd * bf2f(rd.w);
        }
        if (i < d1) {
            int rem = d1 - i, base = s1e + i;
            int ca = cols_s[base];
            float va = vals_s[base];
            int cb = 0, cc = 0, cd = 0;
            float vb = 0.f, vc = 0.f, vd = 0.f;
            if (rem > 1) { cb = cols_s[base + 1]; vb = vals_s[base + 1]; }
            if (rem > 2) { cc = cols_s[base + 2]; vc = vals_s[base + 2]; }
            if (rem > 3) { cd = cols_s[base + 3]; vd = vals_s[base + 3]; }
            ushort4 ra = ((const ushort4*)zsrc)[(size_t)ca * 64 + lane];
            ushort4 rb = (rem > 1) ? ((const ushort4*)zsrc)[(size_t)cb * 64 + lane] : make_ushort4(0,0,0,0);
            ushort4 rc = (rem > 2) ? ((const ushort4*)zsrc)[(size_t)cc * 64 + lane] : make_ushort4(0,0,0,0);
            ushort4 rd = (rem > 3) ? ((const ushort4*)zsrc)[(size_t)cd * 64 + lane] : make_ushort4(0,0,0,0);
            az1.x += va * bf2f(ra.x) + vb * bf2f(rb.x) + vc * bf2f(rc.x) + vd * bf2f(rd.x);
            az1.y += va * bf2f(ra.y) + vb * bf2f(rb.y) + vc * bf2f(rc.y) + vd * bf2f(rd.y);
            az1.z += va * bf2f(ra.z) + vb * bf2f(rb.z) + vc * bf2f(rc.z) + vd * bf2f(rd.z);
            az1.w += va * bf2f(ra.w) + vb * bf2f(rb.w) + vc * bf2f(rc.w) + vd * bf2f(rd.w);
        }
    }

    // ---- z@M via MFMA: only when M != 0 (block-uniform branch) ----
    if (usem) {
        int m = lane & 15, quad = lane >> 4;
        int t0 = wv * 2, t1 = wv * 2 + 1;
        int arow_g = r0 + m;
        bool aok = arow_g < N;
        f32x4 acc0 = {0.f, 0.f, 0.f, 0.f};
        f32x4 acc1 = {0.f, 0.f, 0.f, 0.f};
        #pragma unroll
        for (int kt = 0; kt < 8; kt++) {
            short8 a = aok ? *(const short8*)(zsrc + (size_t)arow_g * 256 + kt * 32 + quad * 8)
                           : short8{0, 0, 0, 0, 0, 0, 0, 0};
            short8 b0 = ((const short8*)Mpk)[(t0 * 8 + kt) * 64 + lane];
            short8 b1 = ((const short8*)Mpk)[(t1 * 8 + kt) * 64 + lane];
            acc0 = __builtin_amdgcn_mfma_f32_16x16x32_bf16(a, b0, acc0, 0, 0, 0);
            acc1 = __builtin_amdgcn_mfma_f32_16x16x32_bf16(a, b1, acc1, 0, 0, 0);
        }
        // C layout: col = lane&15, row = quad*4 + r
        #pragma unroll
        for (int r = 0; r < 4; r++) {
            gs[quad * 4 + r][t0 * 16 + m] = (uint16_t)f2bf(acc0[r]);
            gs[quad * 4 + r][t1 * 16 + m] = (uint16_t)f2bf(acc1[r]);
        }
    }

    // ---- alpha RNN update for both rows ----
    float4 wih0 = ((const float4*)W_ih)[lane];
    float4 wih1 = ((const float4*)(W_ih + DD))[lane];
    float z00 = bf2f(zr0.x), z01 = bf2f(zr0.y), z02 = bf2f(zr0.z), z03 = bf2f(zr0.w);
    float z10 = bf2f(zr1.x), z11 = bf2f(zr1.y), z12 = bf2f(zr1.z), z13 = bf2f(zr1.w);
    float s00 = z00 * wih0.x + z01 * wih0.y + z02 * wih0.z + z03 * wih0.w;
    float s01 = z00 * wih1.x + z01 * wih1.y + z02 * wih1.z + z03 * wih1.w;
    float s10 = z10 * wih0.x + z11 * wih0.y + z12 * wih0.z + z13 * wih0.w;
    float s11 = z10 * wih1.x + z11 * wih1.y + z12 * wih1.z + z13 * wih1.w;
    #pragma unroll
    for (int off = 32; off >= 1; off >>= 1) {
        s00 += __shfl_down(s00, off, 64);
        s01 += __shfl_down(s01, off, 64);
        s10 += __shfl_down(s10, off, 64);
        s11 += __shfl_down(s11, off, 64);
    }
    float alph0 = 0.f, alph1 = 0.f;
    if (lane == 0) {
        float bi0 = b_ih[0] + b_hh[0], bi1 = b_ih[1] + b_hh[1];
        float wh0 = W_hh[0], wh1 = W_hh[1], wh2 = W_hh[2], wh3 = W_hh[3];
        if (ok0) {
            float h0 = hbuf[g0 * 2], h1 = hbuf[g0 * 2 + 1];
            float anew = alpha[g0] * tanhf(s00 + bi0 + h0 * wh0 + h1 * wh1)
                       + tanhf(s01 + bi1 + h0 * wh2 + h1 * wh3);
            alpha[g0] = anew;
            alph0 = 0.5f / (1.f + expf(-anew));
        }
        if (ok1) {
            float h0 = hbuf[g1 * 2], h1 = hbuf[g1 * 2 + 1];
            float anew = alpha[g1] * tanhf(s10 + bi0 + h0 * wh0 + h1 * wh1)
                       + tanhf(s11 + bi1 + h0 * wh2 + h1 * wh3);
            alpha[g1] = anew;
            alph1 = 0.5f / (1.f + expf(-anew));
        }
    }
    alph0 = __shfl(alph0, 0, 64);
    alph1 = __shfl(alph1, 0, 64);

    if (usem) __syncthreads();   // only needed to publish gs

    // ---- combine + RK4 for this wave's two rows ----
    #pragma unroll
    for (int rr = 0; rr < 2; rr++) {
        int rowloc = (rr == 0) ? row0 : row1;
        int grow = (rr == 0) ? g0 : g1;
        bool ok = (rr == 0) ? ok0 : ok1;
        if (!ok) continue;
        float4 azv = (rr == 0) ? az0 : az1;
        ushort4 z4 = (rr == 0) ? zr0 : zr1;
        float al = (rr == 0) ? alph0 : alph1;
        size_t b4 = (size_t)grow * 64 + lane;
        float gv0 = 0.f, gv1 = 0.f, gv2 = 0.f, gv3 = 0.f;
        if (usem) {
            ushort4 g4 = *(const ushort4*)&gs[rowloc][lane * 4];
            gv0 = bf2f(g4.x); gv1 = bf2f(g4.y); gv2 = bf2f(g4.z); gv3 = bf2f(g4.w);
        }
        float4 x4 = make_float4(0.f, 0.f, 0.f, 0.f);
        if (lane < 32) {
            ushort4 v = ((const ushort4*)xb)[(size_t)grow * 32 + lane];
            x4.x = bf2f(v.x); x4.y = bf2f(v.y); x4.z = bf2f(v.z); x4.w = bf2f(v.w);
        }
        float zv0 = bf2f(z4.x), zv1 = bf2f(z4.y), zv2 = bf2f(z4.z), zv3 = bf2f(z4.w);
        float f0 = al * (azv.x - zv0) + gv0 + x4.x;
        float f1 = al * (azv.y - zv1) + gv1 + x4.y;
        float f2 = al * (azv.z - zv2) + gv2 + x4.z;
        float f3 = al * (azv.w - zv3) + gv3 + x4.w;
        if (mode == 0) {
            ushort4 o;
            o.x = (uint16_t)f2bf(zv0 + c1 * f0); o.y = (uint16_t)f2bf(zv1 + c1 * f1);
            o.z = (uint16_t)f2bf(zv2 + c1 * f2); o.w = (uint16_t)f2bf(zv3 + c1 * f3);
            ((ushort4*)zout)[b4] = o;
        } else if (mode == 1) {
            ushort4 zb = ((const ushort4*)znb)[b4];
            float zb0 = bf2f(zb.x), zb1 = bf2f(zb.y), zb2 = bf2f(zb.z), zb3 = bf2f(zb.w);
            float z20 = zb0 + c1 * f0, z21 = zb1 + c1 * f1;
            float z22 = zb2 + c1 * f2, z23 = zb3 + c1 * f3;
            ushort4 o, p;
            o.x = (uint16_t)f2bf(z20); o.y = (uint16_t)f2bf(z21);
            o.z = (uint16_t)f2bf(z22); o.w = (uint16_t)f2bf(z23);
            p.x = (uint16_t)f2bf(zv0 + 2.f * z20 - 3.f * zb0);
            p.y = (uint16_t)f2bf(zv1 + 2.f * z21 - 3.f * zb1);
            p.z = (uint16_t)f2bf(zv2 + 2.f * z22 - 3.f * zb2);
            p.w = (uint16_t)f2bf(zv3 + 2.f * z23 - 3.f * zb3);
            ((ushort4*)zout)[b4] = o;
            ((ushort4*)Pout)[b4] = p;
        } else if (mode == 2) {
            ushort4 zb = ((const ushort4*)znb)[b4];
            ushort4 o;
            o.x = (uint16_t)f2bf(bf2f(zb.x) + c1 * f0);
            o.y = (uint16_t)f2bf(bf2f(zb.y) + c1 * f1);
            o.z = (uint16_t)f2bf(bf2f(zb.z) + c1 * f2);
            o.w = (uint16_t)f2bf(bf2f(zb.w) + c1 * f3);
            ((ushort4*)zout)[b4] = o;
        } else {
            // znew = znb + (P + z3 - znb)/3 + c2*f
            ushort4 zb = ((const ushort4*)znb)[b4];
            ushort4 p4 = ((const ushort4*)Pin)[b4];
            const float third = 1.f / 3.f;
            float zb0 = bf2f(zb.x), zb1 = bf2f(zb.y), zb2 = bf2f(zb.z), zb3 = bf2f(zb.w);
            float r0v = zb0 + (bf2f(p4.x) + zv0 - zb0) * third + c2 * f0;
            float r1v = zb1 + (bf2f(p4.y) + zv1 - zb1) * third + c2 * f1;
            float r2v = zb2 + (bf2f(p4.z) + zv2 - zb2) * third + c2 * f2;
            float r3v = zb3 + (bf2f(p4.w) + zv3 - zb3) * third + c2 * f3;
            if (mode == 3) {
                ushort4 o;
                o.x = (uint16_t)f2bf(r0v); o.y = (uint16_t)f2bf(r1v);
                o.z = (uint16_t)f2bf(r2v); o.w = (uint16_t)f2bf(r3v);
                ((ushort4*)zout)[b4] = o;
            } else {
                if (lane < 32) {
                    float4 o;
                    o.x = r0v; o.y = r1v; o.z = r2v; o.w = r3v;
                    ((float4*)out)[(size_t)grow * 32 + lane] = o;
                }
            }
        }
    }
}

__global__ void k_fill(float* __restrict__ out, int n, float v) {
    int idx = blockIdx.x * blockDim.x + threadIdx.x;
    if (idx < n) out[idx] = v;
}

static inline size_t alignup(size_t v) { return (v + 255) & ~(size_t)255; }

extern "C" void kernel_launch(void* const* d_in, const int* in_sizes, int n_in,
                              void* d_out, int out_size, void* d_ws, size_t ws_size,
                              hipStream_t stream) {
    const float* x      = (const float*)d_in[0];
    const int*   erow   = (const int*)d_in[1];
    const int*   ecol   = (const int*)d_in[2];
    const float* evals  = (const float*)d_in[3];
    const float* W_ih   = (const float*)d_in[4];
    const float* W_hh   = (const float*)d_in[5];
    const float* b_ih   = (const float*)d_in[6];
    const float* b_hh   = (const float*)d_in[7];
    const float* h      = (const float*)d_in[8];
    const float* alpha0 = (const float*)d_in[9];
    const float* W      = (const float*)d_in[10];
    const float* dvec   = (const float*)d_in[11];

    int N = in_sizes[0] / DINF;
    int E = in_sizes[1];

    char* w = (char*)d_ws;
    uint16_t* znb = (uint16_t*)w; w += alignup((size_t)N * DD * 2);   //  51.2 MB
    uint16_t* B1  = (uint16_t*)w; w += alignup((size_t)N * DD * 2);   //  51.2 MB (z1 / z3)
    uint16_t* P   = (uint16_t*)w; w += alignup((size_t)N * DD * 2);   //  51.2 MB (D-fold)
    uint16_t* xb  = (uint16_t*)w; w += alignup((size_t)N * DINF * 2); //  25.6 MB
    float* alpha = (float*)w;     w += alignup((size_t)N * 4);
    uint16_t* Mpk = (uint16_t*)w; w += alignup((size_t)DD * DD * 2);
    int* counts = (int*)w;        w += alignup((size_t)(N + 1) * 4);  // reused as cursor
    int* row_ptr = (int*)w;       w += alignup((size_t)(N + 1) * 4);
    int* blksum = (int*)w;        w += alignup((size_t)1024 * 4);
    int* cols_s = (int*)w;        w += alignup((size_t)E * 4);
    float* vals_s = (float*)w;    w += alignup((size_t)E * 4);
    int* mnz = (int*)w;           w += alignup((size_t)4);            // M-nonzero flag
    size_t need = (size_t)(w - (char*)d_ws);   // ~188 MB

    // B2 (z2) lives in d_out (N*128 f32 = N*256 bf16 exactly); dead after eval3's
    // gather; final mode-4 eval overwrites d_out with the fp32 result.
    uint16_t* B2 = (uint16_t*)d_out;

    if (ws_size < need) {
        k_fill<<<(out_size + 255) / 256, 256, 0, stream>>>((float*)d_out, out_size, 1000.0f);
        return;
    }

    int n1 = N + 1, nb = (n1 + 1023) / 1024;
    hipMemsetAsync(counts, 0, (size_t)n1 * 4, stream);
    hipMemsetAsync(mnz, 0, 4, stream);
    k_hist<<<(E + 255) / 256, 256, 0, stream>>>(erow, counts, E);
    k_scan1<<<nb, 1024, 0, stream>>>(counts, row_ptr, blksum, n1);
    k_scan2<<<1, 1024, 0, stream>>>(blksum, nb);
    k_scan3<<<(n1 + 255) / 256, 256, 0, stream>>>(blksum, row_ptr, counts, n1);
    k_scatter<<<(E + 255) / 256, 256, 0, stream>>>(erow, ecol, evals, counts, cols_s, vals_s, E);

    k_build_m<<<DD, DD, 0, stream>>>(W, dvec, Mpk, mnz);
    k_init<<<(N * 64 + 255) / 256, 256, 0, stream>>>(x, alpha0, znb, xb, alpha, N);

    const float dt = 0.45f;  // T_END / N_STEPS
    int ge = (N + 15) / 16;
    for (int s = 0; s < 2; s++) {
        // eval1: znb -> z1 (B1)
        k_fused<<<ge, 512, 0, stream>>>(znb, znb, B1, nullptr, nullptr, nullptr,
                                        Mpk, xb, mnz, row_ptr, cols_s, vals_s,
                                        W_ih, W_hh, b_ih, b_hh, h, alpha,
                                        N, 0, 0.5f * dt, 0.f);
        // eval2: z1 (B1) -> z2 (B2=d_out), D -> P
        k_fused<<<ge, 512, 0, stream>>>(B1, znb, B2, P, nullptr, nullptr,
                                        Mpk, xb, mnz, row_ptr, cols_s, vals_s,
                                        W_ih, W_hh, b_ih, b_hh, h, alpha,
                                        N, 1, 0.5f * dt, 0.f);
        // eval3: z2 (B2) -> z3 (B1)
        k_fused<<<ge, 512, 0, stream>>>(B2, znb, B1, nullptr, nullptr, nullptr,
                                        Mpk, xb, mnz, row_ptr, cols_s, vals_s,
                                        W_ih, W_hh, b_ih, b_hh, h, alpha,
                                        N, 2, dt, 0.f);
        // eval4: z3 (B1) -> znew
        if (s == 0) {
            k_fused<<<ge, 512, 0, stream>>>(B1, znb, znb, nullptr, P, nullptr,
                                            Mpk, xb, mnz, row_ptr, cols_s, vals_s,
                                            W_ih, W_hh, b_ih, b_hh, h, alpha,
                                            N, 3, 0.f, dt / 6.f);
        } else {
            // final: emit fp32 output directly (first 128 cols)
            k_fused<<<ge, 512, 0, stream>>>(B1, znb, nullptr, nullptr, P,
                                            (float*)d_out,
                                            Mpk, xb, mnz, row_ptr, cols_s, vals_s,
                                            W_ih, W_hh, b_ih, b_hh, h, alpha,
                                            N, 4, 0.f, dt / 6.f);
        }
    }
}